// Round 6
// baseline (20452.776 us; speedup 1.0000x reference)
//
#include <hip/hip_runtime.h>
#include <hip/hip_bf16.h>

// Problem constants
#define NB 32      // batch
#define TO 64      // output tokens
#define TT 65      // decode steps (To+1)
#define TI 512     // encoder time
#define VV 10000   // vocab
#define HH 512     // hidden
#define G4 2048    // 4*H
#define SOS_ID 1
#define EOS_ID 2
#define NBLK 256   // persistent grid; two independent halves of 128
#define HBLK 128

typedef unsigned uvec4 __attribute__((ext_vector_type(4)));

// ---------------------------------------------------------------------------
// Coherent (agent-scope, cache-bypassing) accessors for cross-block state.
// Read-only data (weights/enc/emb) stays on the normal cached path.
// ---------------------------------------------------------------------------
__device__ __forceinline__ float2 cload2(const float* p) {
    unsigned long long v = __hip_atomic_load((const unsigned long long*)p,
                                             __ATOMIC_RELAXED, __HIP_MEMORY_SCOPE_AGENT);
    float2 r;
    r.x = __uint_as_float((unsigned)(v & 0xffffffffull));
    r.y = __uint_as_float((unsigned)(v >> 32));
    return r;
}
__device__ __forceinline__ void cstore(float* p, float v) {
    __hip_atomic_store((unsigned*)p, __float_as_uint(v),
                       __ATOMIC_RELAXED, __HIP_MEMORY_SCOPE_AGENT);
}

// Fence-free half-grid barrier: every wave drains its own stores, block-sync,
// then one thread rendezvous on a relaxed counter. No L2 flush ever.
__device__ __forceinline__ void gbar(int* cnt, int& bt) {
    asm volatile("s_waitcnt vmcnt(0) lgkmcnt(0)" ::: "memory");
    __syncthreads();
    bt += HBLK;
    if (threadIdx.x == 0) {
        __hip_atomic_fetch_add(cnt, 1, __ATOMIC_RELAXED, __HIP_MEMORY_SCOPE_AGENT);
        while (__hip_atomic_load(cnt, __ATOMIC_RELAXED, __HIP_MEMORY_SCOPE_AGENT) < bt)
            __builtin_amdgcn_s_sleep(1);
    }
    __syncthreads();
}

__device__ __forceinline__ float bf2f(unsigned u16) {  // bf16 in low 16 bits
    return __uint_as_float(u16 << 16);
}

// ---------------------------------------------------------------------------
// Fused LSTM phase compute (x already staged in xs[K]): block = 1 n, 64 m
// (mc slice), 4 gates; waves = 4-way k-split; LDS combine; gating inline.
// Weight Wt is k-major [K][2048]; wave reads 64 consecutive floats per gate.
// ---------------------------------------------------------------------------
template <int KQ>  // K/4: 384 (L0) or 256 (L1,L2)
__device__ __forceinline__ void lstm_compute(
    const float* __restrict__ Wt, const float* __restrict__ bi,
    const float* __restrict__ bh, float* __restrict__ hout,
    float& creg, float* __restrict__ mlprow,
    const float* xs, float* red, int mc, int n) {
    int tid = threadIdx.x, lane = tid & 63, kh = tid >> 6;
    int m = mc * 64 + lane;
    const float* wp = Wt + (long)(kh * KQ) * 2048 + m;
    const float* xp = xs + kh * KQ;
    float a0 = 0.f, a1 = 0.f, a2 = 0.f, a3 = 0.f;
#pragma unroll 8
    for (int k = 0; k < KQ; k++) {
        float x = xp[k];
        const float* r = wp + (long)k * 2048;
        a0 = fmaf(r[0], x, a0);
        a1 = fmaf(r[512], x, a1);
        a2 = fmaf(r[1024], x, a2);
        a3 = fmaf(r[1536], x, a3);
    }
    if (kh) {
        float* rb = red + (kh - 1) * 256 + lane;
        rb[0] = a0; rb[64] = a1; rb[128] = a2; rb[192] = a3;
    }
    __syncthreads();
    if (kh == 0) {
        a0 += red[lane] + red[256 + lane] + red[512 + lane];
        a1 += red[64 + lane] + red[320 + lane] + red[576 + lane];
        a2 += red[128 + lane] + red[384 + lane] + red[640 + lane];
        a3 += red[192 + lane] + red[448 + lane] + red[704 + lane];
        float gi = a0 + bi[m] + bh[m];
        float gf = a1 + bi[512 + m] + bh[512 + m];
        float gg = a2 + bi[1024 + m] + bh[1024 + m];
        float go = a3 + bi[1536 + m] + bh[1536 + m];
        float si = 1.f / (1.f + expf(-gi));
        float sf = 1.f / (1.f + expf(-gf));
        float so = 1.f / (1.f + expf(-go));
        float c2 = sf * creg + si * tanhf(gg);
        creg = c2;
        float hv = so * tanhf(c2);
        cstore(&hout[n * 512 + m], hv);
        if (mlprow) mlprow[(long)n * 1024 + m] = hv;
    }
    __syncthreads();
}

// ---------------------------------------------------------------------------
// Persistent decode loop: 65 steps x 5 phases; two independent batch halves.
// ---------------------------------------------------------------------------
__global__ __launch_bounds__(256, 1) void decode_loop(
    const float* __restrict__ Wt0, const float* __restrict__ Wt1,
    const float* __restrict__ Wt2, const float* __restrict__ emb,
    const int* __restrict__ tokens, const unsigned short* __restrict__ encb,
    const float* __restrict__ b_ih0, const float* __restrict__ b_hh0,
    const float* __restrict__ b_ih_r, const float* __restrict__ b_hh_r,
    float* __restrict__ hbuf, float* __restrict__ attc,
    float* __restrict__ scor, float* __restrict__ mlpin, int* cnt) {
    __shared__ float smem[4096];   // x-stage (<=1536) | red at +3072 (768)
    int tid = threadIdx.x, b = blockIdx.x;
    int half = b >> 7, bb = b & 127;
    int* mycnt = cnt + half * 64;
    int bt = 0;
    int mc = bb & 7;               // weight-column slice -> stable XCD (b%8)
    int nl = bb >> 3;              // n within half (16)
    int n = half * 16 + nl;
    float c0r = 0.f, c1r = 0.f, c2r = 0.f;
    float* red = smem + 3072;

    for (int t = 0; t < TT; t++) {
        int rp = t & 1, wp = rp ^ 1;
        float* h0r = hbuf + (rp * 3 + 0) * NB * HH;
        float* h0w = hbuf + (wp * 3 + 0) * NB * HH;
        float* h1r = hbuf + (rp * 3 + 1) * NB * HH;
        float* h1w = hbuf + (wp * 3 + 1) * NB * HH;
        float* h2r = hbuf + (rp * 3 + 2) * NB * HH;
        float* h2w = hbuf + (wp * 3 + 2) * NB * HH;

        // ---- phase 1: L0 LSTM, x = [emb(tok) | attc | h0r], K=1536
        {
            int row = (t == 0) ? SOS_ID : tokens[n * TO + t - 1];
#pragma unroll
            for (int i = 0; i < 3; i++) {
                int k = (tid + i * 256) * 2;
                float2 v;
                if (k < 512) v = *(const float2*)(emb + (long)row * 512 + k);
                else if (k < 1024) v = cload2(attc + n * 512 + (k - 512));
                else v = cload2(h0r + n * 512 + (k - 1024));
                smem[k] = v.x; smem[k + 1] = v.y;
            }
        }
        __syncthreads();
        lstm_compute<384>(Wt0, b_ih0, b_hh0, h0w, c0r, nullptr, smem, red, mc, n);
        gbar(mycnt, bt);

        // ---- phase 2: L1 LSTM, x = [h0' | h1r], K=1024
#pragma unroll
        for (int i = 0; i < 2; i++) {
            int k = (tid + i * 256) * 2;
            float2 v = (k < 512) ? cload2(h0w + n * 512 + k)
                                 : cload2(h1r + n * 512 + (k - 512));
            smem[k] = v.x; smem[k + 1] = v.y;
        }
        __syncthreads();
        lstm_compute<256>(Wt1, b_ih_r, b_hh_r, h1w, c1r, nullptr, smem, red, mc, n);
        gbar(mycnt, bt);

        // ---- phase 3: L2 LSTM, x = [h1' | h2r], K=1024 (h2' -> mlpin)
#pragma unroll
        for (int i = 0; i < 2; i++) {
            int k = (tid + i * 256) * 2;
            float2 v = (k < 512) ? cload2(h1w + n * 512 + k)
                                 : cload2(h2r + n * 512 + (k - 512));
            smem[k] = v.x; smem[k + 1] = v.y;
        }
        __syncthreads();
        lstm_compute<256>(Wt2, b_ih_r + G4, b_hh_r + G4, h2w, c2r,
                          mlpin + (long)t * NB * 1024, smem, red, mc, n);
        gbar(mycnt, bt);

        // ---- phase 4: scores[na][ti] = dot(h2'[na], enc[na][ti]) (bf16 enc)
        {
            int na = half * 16 + (bb >> 3), tiq = bb & 7;
            {
                float2 v = cload2(h2w + na * 512 + tid * 2);
                smem[tid * 2] = v.x; smem[tid * 2 + 1] = v.y;
            }
            __syncthreads();
            int til = tid & 63, kh2 = tid >> 6;
            int ti = tiq * 64 + til;
            const uvec4* e4 = (const uvec4*)(encb + ((long)na * TI + ti) * 512 + kh2 * 128);
            const float4* h4 = (const float4*)(smem + kh2 * 128);
            float s = 0.f;
#pragma unroll 4
            for (int q = 0; q < 16; q++) {
                uvec4 e = __builtin_nontemporal_load(e4 + q);
                float4 x0 = h4[q * 2], x1 = h4[q * 2 + 1];
                s += bf2f(e.x & 0xffffu) * x0.x + bf2f(e.x >> 16) * x0.y +
                     bf2f(e.y & 0xffffu) * x0.z + bf2f(e.y >> 16) * x0.w +
                     bf2f(e.z & 0xffffu) * x1.x + bf2f(e.z >> 16) * x1.y +
                     bf2f(e.w & 0xffffu) * x1.z + bf2f(e.w >> 16) * x1.w;
            }
            float* sred = smem + 512;
            sred[tid] = s;
            __syncthreads();
            if (tid < 64) {
                float sv = sred[tid] + sred[tid + 64] + sred[tid + 128] + sred[tid + 192];
                cstore(&scor[na * 512 + tiq * 64 + tid], sv);
            }
        }
        gbar(mycnt, bt);

        // ---- phase 5: softmax + apply -> attc, mlpin[t][:][512:1024]
        {
            int na = half * 16 + (bb >> 3), hq = bb & 7;
            float* sw = smem;           // 512 weights
            float* rr = smem + 512;     // 256 reduce
            float* prt = smem + 768;    // 512 partials
            {
                float2 v = cload2(scor + na * 512 + tid * 2);
                sw[tid * 2] = v.x; sw[tid * 2 + 1] = v.y;
            }
            __syncthreads();
            float s0 = sw[tid], s1 = sw[tid + 256];
            rr[tid] = fmaxf(s0, s1);
            __syncthreads();
            for (int st = 128; st > 0; st >>= 1) {
                if (tid < st) rr[tid] = fmaxf(rr[tid], rr[tid + st]);
                __syncthreads();
            }
            float mx = rr[0];
            __syncthreads();
            float e0 = expf(s0 - mx), e1 = expf(s1 - mx);
            rr[tid] = e0 + e1;
            __syncthreads();
            for (int st = 128; st > 0; st >>= 1) {
                if (tid < st) rr[tid] += rr[tid + st];
                __syncthreads();
            }
            float inv = 1.f / rr[0];
            __syncthreads();
            sw[tid] = e0 * inv; sw[tid + 256] = e1 * inv;
            __syncthreads();
            int hp = tid & 31, tih = tid >> 5;          // 32 h-pairs x 8 ti-blocks
            int h = hq * 64 + hp * 2;
            float a0 = 0.f, a1 = 0.f;
            const unsigned short* eb = encb + ((long)na * TI + tih * 64) * 512 + h;
#pragma unroll 8
            for (int t2 = 0; t2 < 64; t2++) {
                unsigned u = __builtin_nontemporal_load((const unsigned*)(eb + (long)t2 * 512));
                float w = sw[tih * 64 + t2];
                a0 = fmaf(w, bf2f(u & 0xffffu), a0);
                a1 = fmaf(w, bf2f(u >> 16), a1);
            }
            prt[tid * 2] = a0; prt[tid * 2 + 1] = a1;
            __syncthreads();
            if (tid < 32) {
                float v0 = 0.f, v1 = 0.f;
#pragma unroll
                for (int q = 0; q < 8; q++) {
                    v0 += prt[(q * 32 + tid) * 2];
                    v1 += prt[(q * 32 + tid) * 2 + 1];
                }
                int hh = hq * 64 + tid * 2;
                cstore(&attc[na * 512 + hh], v0);
                cstore(&attc[na * 512 + hh + 1], v1);
                float* mp = mlpin + ((long)t * NB + na) * 1024 + 512 + hh;
                mp[0] = v0; mp[1] = v1;
            }
        }
        gbar(mycnt, bt);
    }
}

// ---------------------------------------------------------------------------
// Weight transpose: Wt[k][j] = concat(A,B)[j][k], zero-padded to Jp columns
// ---------------------------------------------------------------------------
__global__ void transpose_cat(const float* __restrict__ A, int KA,
                              const float* __restrict__ B, int KB,
                              int J, int Jp, float* __restrict__ Wt) {
    int K = KA + KB;
    long total = (long)K * Jp;
    for (long idx = (long)blockIdx.x * 256 + threadIdx.x; idx < total;
         idx += (long)gridDim.x * 256) {
        int j = (int)(idx % Jp);
        int k = (int)(idx / Jp);
        float v = 0.f;
        if (j < J) v = (k < KA) ? A[(long)j * KA + k] : B[(long)j * KB + (k - KA)];
        Wt[idx] = v;
    }
}

// enc (fp32) -> bf16 (RNE), vectorized
__global__ void enc_to_bf16(const float* __restrict__ in,
                            unsigned short* __restrict__ outp, long n4) {
    for (long i = (long)blockIdx.x * 256 + threadIdx.x; i < n4;
         i += (long)gridDim.x * 256) {
        float4 v = ((const float4*)in)[i];
        ushort4 o;
        unsigned u;
        u = __float_as_uint(v.x); o.x = (unsigned short)((u + 0x7fffu + ((u >> 16) & 1u)) >> 16);
        u = __float_as_uint(v.y); o.y = (unsigned short)((u + 0x7fffu + ((u >> 16) & 1u)) >> 16);
        u = __float_as_uint(v.z); o.z = (unsigned short)((u + 0x7fffu + ((u >> 16) & 1u)) >> 16);
        u = __float_as_uint(v.w); o.w = (unsigned short)((u + 0x7fffu + ((u >> 16) & 1u)) >> 16);
        ((ushort4*)outp)[i] = o;
    }
}

// ---------------------------------------------------------------------------
// Full-K batched GEMM with fused bias(+tanh). Thread owns 2 j's (j0, j0+64).
// remap=0: out[row][J]; remap=1: out[(nn*TT+t)*VV + j]
// ---------------------------------------------------------------------------
__global__ void gemm_full(const float* __restrict__ Wt, int Jp, int J, int K,
                          const float* __restrict__ X,
                          const float* __restrict__ bias,
                          float* __restrict__ out, int act, int remap) {
    __shared__ float xs[64 * 36];
    int t = blockIdx.y;
    int m0 = t * 32;
    int lane = threadIdx.x & 63;
    int wv = threadIdx.x >> 6;
    int j0 = blockIdx.x * 512 + wv * 128 + lane;
    float acc0[32], acc1[32];
#pragma unroll
    for (int q = 0; q < 32; q++) { acc0[q] = 0.f; acc1[q] = 0.f; }

    for (int kc = 0; kc < K; kc += 64) {
        __syncthreads();
        for (int idx = threadIdx.x; idx < 64 * 32; idx += 256) {
            int n = idx >> 6, k = idx & 63;
            xs[k * 36 + n] = X[(long)(m0 + n) * K + kc + k];
        }
        __syncthreads();
        const float* wpp = Wt + (long)kc * Jp + j0;
#pragma unroll 4
        for (int k = 0; k < 64; k++) {
            float w0 = wpp[(long)k * Jp];
            float w1 = wpp[(long)k * Jp + 64];
            const float4* xv = (const float4*)(xs + k * 36);
#pragma unroll
            for (int q = 0; q < 8; q++) {
                float4 x4 = xv[q];
                acc0[4 * q + 0] += w0 * x4.x;
                acc0[4 * q + 1] += w0 * x4.y;
                acc0[4 * q + 2] += w0 * x4.z;
                acc0[4 * q + 3] += w0 * x4.w;
                acc1[4 * q + 0] += w1 * x4.x;
                acc1[4 * q + 1] += w1 * x4.y;
                acc1[4 * q + 2] += w1 * x4.z;
                acc1[4 * q + 3] += w1 * x4.w;
            }
        }
    }
#pragma unroll
    for (int nn = 0; nn < 32; nn++) {
        long row = remap ? ((long)nn * TT + t) : (long)(m0 + nn);
        float* po = out + row * (remap ? (long)VV : (long)J);
        int ja = j0, jb = j0 + 64;
        if (ja < J) {
            float v = acc0[nn] + bias[ja];
            if (act) v = tanhf(v);
            po[ja] = v;
        }
        if (jb < J) {
            float v = acc1[nn] + bias[jb];
            if (act) v = tanhf(v);
            po[jb] = v;
        }
    }
}

// ---------------------------------------------------------------------------
// Loss: per-(n,t) logsumexp NLL, then mean
// ---------------------------------------------------------------------------
__global__ void loss_rows(const float* __restrict__ out, const int* __restrict__ tokens,
                          float* __restrict__ nll) {
    __shared__ float red[256];
    int row = blockIdx.x;  // n*TT + t
    int n = row / TT, t = row % TT;
    const float* y = out + (long)row * VV;
    int tid = threadIdx.x;
    float m = -1e30f;
    for (int v = tid; v < VV; v += 256) m = fmaxf(m, y[v]);
    red[tid] = m;
    __syncthreads();
    for (int s = 128; s > 0; s >>= 1) {
        if (tid < s) red[tid] = fmaxf(red[tid], red[tid + s]);
        __syncthreads();
    }
    m = red[0];
    __syncthreads();
    float sum = 0.f;
    for (int v = tid; v < VV; v += 256) sum += expf(y[v] - m);
    red[tid] = sum;
    __syncthreads();
    for (int s = 128; s > 0; s >>= 1) {
        if (tid < s) red[tid] += red[tid + s];
        __syncthreads();
    }
    if (tid == 0) {
        int target = (t < TO) ? tokens[n * TO + t] : EOS_ID;
        float lse = m + logf(red[0]);
        nll[row] = lse - y[target];
    }
}

__global__ void loss_final(const float* __restrict__ nll, float* __restrict__ out_loss) {
    __shared__ float red[256];
    int tid = threadIdx.x;
    float s = 0.f;
    for (int i = tid; i < NB * TT; i += 256) s += nll[i];
    red[tid] = s;
    __syncthreads();
    for (int k = 128; k > 0; k >>= 1) {
        if (tid < k) red[tid] += red[tid + k];
        __syncthreads();
    }
    if (tid == 0) *out_loss = red[0] / (float)(NB * TT);
}

// ---------------------------------------------------------------------------
extern "C" void kernel_launch(void* const* d_in, const int* in_sizes, int n_in,
                              void* d_out, int out_size, void* d_ws, size_t ws_size,
                              hipStream_t stream) {
    const int* padded   = (const int*)d_in[0];
    const float* enc    = (const float*)d_in[1];
    const float* emb    = (const float*)d_in[2];
    const float* W_ih0  = (const float*)d_in[3];
    const float* W_hh0  = (const float*)d_in[4];
    const float* b_ih0  = (const float*)d_in[5];
    const float* b_hh0  = (const float*)d_in[6];
    const float* W_ih_r = (const float*)d_in[7];
    const float* W_hh_r = (const float*)d_in[8];
    const float* b_ih_r = (const float*)d_in[9];
    const float* b_hh_r = (const float*)d_in[10];
    const float* W1     = (const float*)d_in[11];
    const float* b1     = (const float*)d_in[12];
    const float* W2     = (const float*)d_in[13];
    const float* b2     = (const float*)d_in[14];
    float* out = (float*)d_out;
    float* ws  = (float*)d_ws;

    // workspace layout (floats), ~65.8 MB total
    float* Wt0  = ws;                        // [1536][2048] k-major
    float* Wt1  = Wt0 + 1536 * 2048;         // [1024][2048]
    float* Wt2  = Wt1 + 1024 * 2048;         // [1024][2048]
    float* Wm1  = Wt2 + 1024 * 2048;         // [1024 k][512 j]
    float* R    = Wm1 + 1024 * 512;          // decode: encbf (16.8MB) | tail: Wm2+y1all
    float* hbuf = R + 6307840;               // [2][3][32][512] ping-pong h
    float* attc = hbuf + 2 * 3 * NB * HH;    // [32][512]
    float* scor = attc + NB * HH;            // [32][512]
    float* mlpin= scor + NB * TI;            // [65][32][1024]
    float* nll  = mlpin + (long)TT * NB * 1024;  // [2080]
    int*   cnt  = (int*)(nll + 2112);        // 2 counters, 256B apart
    unsigned short* encb = (unsigned short*)R;          // decode-phase alias
    float* Wm2  = R;                                    // tail alias  [512][10240]
    float* y1all= R + 5242880;                          // tail alias  [2080][512]

    // init: zero h (both parities) + attc + scor (contiguous), and counters
    hipMemsetAsync(hbuf, 0, (size_t)(2 * 3 * NB * HH + 2 * NB * HH) * sizeof(float), stream);
    hipMemsetAsync(cnt, 0, 512, stream);

    // prep: k-major weight transposes + enc->bf16 (before decode; L2 warms on Wt)
    transpose_cat<<<1024, 256, 0, stream>>>(W1, 1024, nullptr, 0, 512, 512, Wm1);
    transpose_cat<<<2048, 256, 0, stream>>>(W_ih0, 1024, W_hh0, 512, G4, G4, Wt0);
    transpose_cat<<<2048, 256, 0, stream>>>(W_ih_r, 512, W_hh_r, 512, G4, G4, Wt1);
    transpose_cat<<<2048, 256, 0, stream>>>(W_ih_r + 2048 * 512, 512,
                                            W_hh_r + 2048 * 512, 512, G4, G4, Wt2);
    enc_to_bf16<<<2048, 256, 0, stream>>>(enc, encb, (long)NB * TI * HH / 4);

    // persistent recurrence
    decode_loop<<<NBLK, 256, 0, stream>>>(Wt0, Wt1, Wt2, emb, padded, encb,
                                          b_ih0, b_hh0, b_ih_r, b_hh_r,
                                          hbuf, attc, scor, mlpin, cnt);

    // deferred MLP over all 2080 rows (Wm2 transpose after decode: alias with encb)
    transpose_cat<<<2048, 256, 0, stream>>>(W2, 512, nullptr, 0, VV, 10240, Wm2);
    gemm_full<<<dim3(1, TT), 256, 0, stream>>>(Wm1, 512, 512, 1024, mlpin, b1,
                                               y1all, 1, 0);
    gemm_full<<<dim3(20, TT), 256, 0, stream>>>(Wm2, 10240, VV, 512, y1all, b2,
                                                out, 0, 1);
    loss_rows<<<NB * TT, 256, 0, stream>>>(out, padded, nll);
    loss_final<<<1, 256, 0, stream>>>(nll, out + (long)NB * TT * VV);
}

// Round 7
// 7181.821 us; speedup vs baseline: 2.8479x; 2.8479x over previous
//
#include <hip/hip_runtime.h>
#include <hip/hip_bf16.h>

// Problem constants
#define NB 32      // batch
#define TO 64      // output tokens
#define TT 65      // decode steps (To+1)
#define TI 512     // encoder time
#define VV 10000   // vocab
#define HH 512     // hidden
#define G4 2048    // 4*H
#define SOS_ID 1
#define EOS_ID 2
#define NBLK 256   // 8 independent groups x 32 blocks
#define GBLK 32    // blocks per group (4 batch rows each)

typedef unsigned uvec4 __attribute__((ext_vector_type(4)));

// ---------------------------------------------------------------------------
// Coherent (agent-scope, cache-bypassing) accessors for cross-block state.
// Read-only data (weights/enc/emb) stays on the normal cached path.
// ---------------------------------------------------------------------------
__device__ __forceinline__ float2 cload2(const float* p) {
    unsigned long long v = __hip_atomic_load((const unsigned long long*)p,
                                             __ATOMIC_RELAXED, __HIP_MEMORY_SCOPE_AGENT);
    float2 r;
    r.x = __uint_as_float((unsigned)(v & 0xffffffffull));
    r.y = __uint_as_float((unsigned)(v >> 32));
    return r;
}
__device__ __forceinline__ void cstore(float* p, float v) {
    __hip_atomic_store((unsigned*)p, __float_as_uint(v),
                       __ATOMIC_RELAXED, __HIP_MEMORY_SCOPE_AGENT);
}

// Fence-free GROUP barrier (32 arrivals on a group-private line).
__device__ __forceinline__ void gbar(int* cnt, int& bt) {
    asm volatile("s_waitcnt vmcnt(0) lgkmcnt(0)" ::: "memory");
    __syncthreads();
    bt += GBLK;
    if (threadIdx.x == 0) {
        __hip_atomic_fetch_add(cnt, 1, __ATOMIC_RELAXED, __HIP_MEMORY_SCOPE_AGENT);
        while (__hip_atomic_load(cnt, __ATOMIC_RELAXED, __HIP_MEMORY_SCOPE_AGENT) < bt)
            __builtin_amdgcn_s_sleep(2);
    }
    __syncthreads();
}

__device__ __forceinline__ float bf2f(unsigned u16) {  // bf16 in low 16 bits
    return __uint_as_float(u16 << 16);
}

// ---------------------------------------------------------------------------
// Persistent decode: 8 groups x 32 blocks; group owns 4 batch rows.
// Per step: 3 fused LSTM phases + scores + softmax/apply, 5 group barriers.
// Weights k-major [K][2048], column c = s*64 + gate*16 + ml  (slice s: 16 m's).
// ---------------------------------------------------------------------------
__global__ __launch_bounds__(256, 1) void decode_loop(
    const float* __restrict__ Wt0, const float* __restrict__ Wt1,
    const float* __restrict__ Wt2, const float* __restrict__ emb,
    const int* __restrict__ tokens, const unsigned short* __restrict__ encb,
    const float* __restrict__ b_ih0, const float* __restrict__ b_hh0,
    const float* __restrict__ b_ih_r, const float* __restrict__ b_hh_r,
    float* __restrict__ hbuf, float* __restrict__ attc,
    float* __restrict__ scor, float* __restrict__ mlpin, int* cnt) {
    __shared__ float smem[7168];          // xs4[1536]*4 (24KB) | sg at 6144 (4KB)
    int tid = threadIdx.x, b = blockIdx.x;
    int g = b >> 5, s = b & 31;           // group, slice (slice s -> XCD s%8)
    int* mycnt = cnt + g * 64;            // 256B-separated counter lines
    int bt = 0;
    int n0 = g * 4;
    int lane = tid & 63, wv = tid >> 6;
    int gn = tid >> 4, gml = tid & 15;    // gating identity (tid<64): n-local, m-local
    int gm = s * 16 + gml;                // global m for gating thread
    float c0r = 0.f, c1r = 0.f, c2r = 0.f;
    float4* xs4 = (float4*)smem;
    float* sg = smem + 6144;

    for (int t = 0; t < TT; t++) {
        int rp = t & 1;
        float* hOld = hbuf + rp * 3 * NB * HH;
        float* hNew = hbuf + (rp ^ 1) * 3 * NB * HH;
        float* h0r = hOld;
        float* h1r = hOld + NB * HH;
        float* h2r = hOld + 2 * NB * HH;
        float* h0w = hNew;
        float* h1w = hNew + NB * HH;
        float* h2w = hNew + 2 * NB * HH;

        // ================= phase 1: L0 LSTM, x=[emb|attc|h0r], K=1536 ======
        for (int nn = 0; nn < 4; nn++) {
            int n = n0 + nn;
            int row = (t == 0) ? SOS_ID : tokens[n * TO + t - 1];
            for (int p = tid; p < 768; p += 256) {
                int k = p * 2;
                float2 v;
                if (k < 512) v = *(const float2*)(emb + (long)row * 512 + k);
                else if (k < 1024) v = cload2(attc + n * 512 + (k - 512));
                else v = cload2(h0r + n * 512 + (k - 1024));
                smem[k * 4 + nn] = v.x;
                smem[(k + 1) * 4 + nn] = v.y;
            }
        }
        __syncthreads();
        {
            const int KQ = 384;
            const float* wp = Wt0 + (long)(wv * KQ) * 2048 + s * 64 + lane;
            const float4* xp = xs4 + wv * KQ;
            float a0 = 0.f, a1 = 0.f, a2 = 0.f, a3 = 0.f;
#pragma unroll 4
            for (int k = 0; k < KQ; k++) {
                float w = wp[(long)k * 2048];
                float4 x = xp[k];
                a0 = fmaf(w, x.x, a0); a1 = fmaf(w, x.y, a1);
                a2 = fmaf(w, x.z, a2); a3 = fmaf(w, x.w, a3);
            }
            float4 r4; r4.x = a0; r4.y = a1; r4.z = a2; r4.w = a3;
            ((float4*)sg)[wv * 64 + lane] = r4;
        }
        __syncthreads();
        if (tid < 64) {
            float ga[4];
#pragma unroll
            for (int gg = 0; gg < 4; gg++) {
                int c = gg * 16 + gml;
                ga[gg] = sg[(0 * 64 + c) * 4 + gn] + sg[(1 * 64 + c) * 4 + gn] +
                         sg[(2 * 64 + c) * 4 + gn] + sg[(3 * 64 + c) * 4 + gn];
            }
            float gi = ga[0] + b_ih0[gm] + b_hh0[gm];
            float gf = ga[1] + b_ih0[512 + gm] + b_hh0[512 + gm];
            float gg_ = ga[2] + b_ih0[1024 + gm] + b_hh0[1024 + gm];
            float go = ga[3] + b_ih0[1536 + gm] + b_hh0[1536 + gm];
            float si = 1.f / (1.f + expf(-gi));
            float sf = 1.f / (1.f + expf(-gf));
            float so = 1.f / (1.f + expf(-go));
            float c2 = sf * c0r + si * tanhf(gg_);
            c0r = c2;
            cstore(&h0w[(n0 + gn) * 512 + gm], so * tanhf(c2));
        }
        gbar(mycnt, bt);

        // ================= phase 2: L1 LSTM, x=[h0w|h1r], K=1024 ===========
        for (int nn = 0; nn < 4; nn++) {
            int n = n0 + nn;
            for (int p = tid; p < 512; p += 256) {
                int k = p * 2;
                float2 v = (k < 512) ? cload2(h0w + n * 512 + k)
                                     : cload2(h1r + n * 512 + (k - 512));
                smem[k * 4 + nn] = v.x;
                smem[(k + 1) * 4 + nn] = v.y;
            }
        }
        __syncthreads();
        {
            const int KQ = 256;
            const float* wp = Wt1 + (long)(wv * KQ) * 2048 + s * 64 + lane;
            const float4* xp = xs4 + wv * KQ;
            float a0 = 0.f, a1 = 0.f, a2 = 0.f, a3 = 0.f;
#pragma unroll 4
            for (int k = 0; k < KQ; k++) {
                float w = wp[(long)k * 2048];
                float4 x = xp[k];
                a0 = fmaf(w, x.x, a0); a1 = fmaf(w, x.y, a1);
                a2 = fmaf(w, x.z, a2); a3 = fmaf(w, x.w, a3);
            }
            float4 r4; r4.x = a0; r4.y = a1; r4.z = a2; r4.w = a3;
            ((float4*)sg)[wv * 64 + lane] = r4;
        }
        __syncthreads();
        if (tid < 64) {
            float ga[4];
#pragma unroll
            for (int gg = 0; gg < 4; gg++) {
                int c = gg * 16 + gml;
                ga[gg] = sg[(0 * 64 + c) * 4 + gn] + sg[(1 * 64 + c) * 4 + gn] +
                         sg[(2 * 64 + c) * 4 + gn] + sg[(3 * 64 + c) * 4 + gn];
            }
            float gi = ga[0] + b_ih_r[gm] + b_hh_r[gm];
            float gf = ga[1] + b_ih_r[512 + gm] + b_hh_r[512 + gm];
            float gg_ = ga[2] + b_ih_r[1024 + gm] + b_hh_r[1024 + gm];
            float go = ga[3] + b_ih_r[1536 + gm] + b_hh_r[1536 + gm];
            float si = 1.f / (1.f + expf(-gi));
            float sf = 1.f / (1.f + expf(-gf));
            float so = 1.f / (1.f + expf(-go));
            float c2 = sf * c1r + si * tanhf(gg_);
            c1r = c2;
            cstore(&h1w[(n0 + gn) * 512 + gm], so * tanhf(c2));
        }
        gbar(mycnt, bt);

        // ================= phase 3: L2 LSTM, x=[h1w|h2r], K=1024 ===========
        for (int nn = 0; nn < 4; nn++) {
            int n = n0 + nn;
            for (int p = tid; p < 512; p += 256) {
                int k = p * 2;
                float2 v = (k < 512) ? cload2(h1w + n * 512 + k)
                                     : cload2(h2r + n * 512 + (k - 512));
                smem[k * 4 + nn] = v.x;
                smem[(k + 1) * 4 + nn] = v.y;
            }
        }
        __syncthreads();
        {
            const int KQ = 256;
            const float* wp = Wt2 + (long)(wv * KQ) * 2048 + s * 64 + lane;
            const float4* xp = xs4 + wv * KQ;
            float a0 = 0.f, a1 = 0.f, a2 = 0.f, a3 = 0.f;
#pragma unroll 4
            for (int k = 0; k < KQ; k++) {
                float w = wp[(long)k * 2048];
                float4 x = xp[k];
                a0 = fmaf(w, x.x, a0); a1 = fmaf(w, x.y, a1);
                a2 = fmaf(w, x.z, a2); a3 = fmaf(w, x.w, a3);
            }
            float4 r4; r4.x = a0; r4.y = a1; r4.z = a2; r4.w = a3;
            ((float4*)sg)[wv * 64 + lane] = r4;
        }
        __syncthreads();
        if (tid < 64) {
            float ga[4];
#pragma unroll
            for (int gg = 0; gg < 4; gg++) {
                int c = gg * 16 + gml;
                ga[gg] = sg[(0 * 64 + c) * 4 + gn] + sg[(1 * 64 + c) * 4 + gn] +
                         sg[(2 * 64 + c) * 4 + gn] + sg[(3 * 64 + c) * 4 + gn];
            }
            float gi = ga[0] + b_ih_r[G4 + gm] + b_hh_r[G4 + gm];
            float gf = ga[1] + b_ih_r[G4 + 512 + gm] + b_hh_r[G4 + 512 + gm];
            float gg_ = ga[2] + b_ih_r[G4 + 1024 + gm] + b_hh_r[G4 + 1024 + gm];
            float go = ga[3] + b_ih_r[G4 + 1536 + gm] + b_hh_r[G4 + 1536 + gm];
            float si = 1.f / (1.f + expf(-gi));
            float sf = 1.f / (1.f + expf(-gf));
            float so = 1.f / (1.f + expf(-go));
            float c2 = sf * c2r + si * tanhf(gg_);
            c2r = c2;
            float hv = so * tanhf(c2);
            cstore(&h2w[(n0 + gn) * 512 + gm], hv);
            mlpin[((long)t * NB + (n0 + gn)) * 1024 + gm] = hv;
        }
        gbar(mycnt, bt);

        // ================= phase 4: scores (8 blocks/n, ti-split 64) =======
        {
            int na = n0 + (s >> 3), tiq = s & 7;
            {
                float2 v = cload2(h2w + na * 512 + tid * 2);
                smem[tid * 2] = v.x; smem[tid * 2 + 1] = v.y;
            }
            __syncthreads();
            int til = tid & 63, kh2 = tid >> 6;
            int ti = tiq * 64 + til;
            const uvec4* e4 = (const uvec4*)(encb + ((long)na * TI + ti) * 512 + kh2 * 128);
            const float4* h4 = (const float4*)(smem + kh2 * 128);
            float sv = 0.f;
#pragma unroll 4
            for (int q = 0; q < 16; q++) {
                uvec4 e = __builtin_nontemporal_load(e4 + q);
                float4 x0 = h4[q * 2], x1 = h4[q * 2 + 1];
                sv += bf2f(e.x & 0xffffu) * x0.x + bf2f(e.x >> 16) * x0.y +
                      bf2f(e.y & 0xffffu) * x0.z + bf2f(e.y >> 16) * x0.w +
                      bf2f(e.z & 0xffffu) * x1.x + bf2f(e.z >> 16) * x1.y +
                      bf2f(e.w & 0xffffu) * x1.z + bf2f(e.w >> 16) * x1.w;
            }
            float* sred = smem + 512;
            sred[tid] = sv;
            __syncthreads();
            if (tid < 64) {
                float sx = sred[tid] + sred[tid + 64] + sred[tid + 128] + sred[tid + 192];
                cstore(&scor[na * 512 + tiq * 64 + tid], sx);
            }
        }
        gbar(mycnt, bt);

        // ================= phase 5: softmax + apply (8 blocks/n, h-split) ==
        {
            int na = n0 + (s >> 3), hq = s & 7;
            float* sw = smem;           // 512 weights
            float* rr = smem + 512;     // 256 reduce
            float* prt = smem + 768;    // 512 partials
            {
                float2 v = cload2(scor + na * 512 + tid * 2);
                sw[tid * 2] = v.x; sw[tid * 2 + 1] = v.y;
            }
            __syncthreads();
            float s0 = sw[tid], s1 = sw[tid + 256];
            rr[tid] = fmaxf(s0, s1);
            __syncthreads();
            for (int st = 128; st > 0; st >>= 1) {
                if (tid < st) rr[tid] = fmaxf(rr[tid], rr[tid + st]);
                __syncthreads();
            }
            float mx = rr[0];
            __syncthreads();
            float e0 = expf(s0 - mx), e1 = expf(s1 - mx);
            rr[tid] = e0 + e1;
            __syncthreads();
            for (int st = 128; st > 0; st >>= 1) {
                if (tid < st) rr[tid] += rr[tid + st];
                __syncthreads();
            }
            float inv = 1.f / rr[0];
            __syncthreads();
            sw[tid] = e0 * inv; sw[tid + 256] = e1 * inv;
            __syncthreads();
            int hp = tid & 31, tih = tid >> 5;   // 32 h-pairs x 8 ti-chunks
            int h = hq * 64 + hp * 2;
            float a0 = 0.f, a1 = 0.f;
            const unsigned short* eb = encb + ((long)na * TI + tih * 64) * 512 + h;
#pragma unroll 8
            for (int t2 = 0; t2 < 64; t2++) {
                unsigned u = __builtin_nontemporal_load((const unsigned*)(eb + (long)t2 * 512));
                float w = sw[tih * 64 + t2];
                a0 = fmaf(w, bf2f(u & 0xffffu), a0);
                a1 = fmaf(w, bf2f(u >> 16), a1);
            }
            prt[tid * 2] = a0; prt[tid * 2 + 1] = a1;
            __syncthreads();
            if (tid < 32) {
                float v0 = 0.f, v1 = 0.f;
#pragma unroll
                for (int q = 0; q < 8; q++) {
                    v0 += prt[(q * 32 + tid) * 2];
                    v1 += prt[(q * 32 + tid) * 2 + 1];
                }
                int hh = hq * 64 + tid * 2;
                cstore(&attc[na * 512 + hh], v0);
                cstore(&attc[na * 512 + hh + 1], v1);
                float* mp = mlpin + ((long)t * NB + na) * 1024 + 512 + hh;
                mp[0] = v0; mp[1] = v1;
            }
        }
        gbar(mycnt, bt);
    }
}

// ---------------------------------------------------------------------------
// LSTM weight transpose with slice-permuted columns:
// Wt[k][c], c = s*64 + gate*16 + ml  <->  j = gate*512 + s*16 + ml
// k < KA: from Wih[j][KA]; else from Whh[j][512]
// ---------------------------------------------------------------------------
__global__ void transpose_lstm(const float* __restrict__ Wih, int KA,
                               const float* __restrict__ Whh,
                               float* __restrict__ Wt) {
    long total = (long)(KA + 512) * 2048;
    for (long idx = (long)blockIdx.x * 256 + threadIdx.x; idx < total;
         idx += (long)gridDim.x * 256) {
        int c = (int)(idx % 2048);
        int k = (int)(idx / 2048);
        int sI = c >> 6, r = c & 63, gg = r >> 4, ml = r & 15;
        int j = gg * 512 + sI * 16 + ml;
        Wt[idx] = (k < KA) ? Wih[(long)j * KA + k] : Whh[(long)j * 512 + (k - KA)];
    }
}

// ---------------------------------------------------------------------------
// Plain transpose for tail GEMMs: Wt[k][j] = A[j][k], zero-padded to Jp
// ---------------------------------------------------------------------------
__global__ void transpose_cat(const float* __restrict__ A, int KA,
                              const float* __restrict__ B, int KB,
                              int J, int Jp, float* __restrict__ Wt) {
    int K = KA + KB;
    long total = (long)K * Jp;
    for (long idx = (long)blockIdx.x * 256 + threadIdx.x; idx < total;
         idx += (long)gridDim.x * 256) {
        int j = (int)(idx % Jp);
        int k = (int)(idx / Jp);
        float v = 0.f;
        if (j < J) v = (k < KA) ? A[(long)j * KA + k] : B[(long)j * KB + (k - KA)];
        Wt[idx] = v;
    }
}

// enc (fp32) -> bf16 (RNE), vectorized
__global__ void enc_to_bf16(const float* __restrict__ in,
                            unsigned short* __restrict__ outp, long n4) {
    for (long i = (long)blockIdx.x * 256 + threadIdx.x; i < n4;
         i += (long)gridDim.x * 256) {
        float4 v = ((const float4*)in)[i];
        ushort4 o;
        unsigned u;
        u = __float_as_uint(v.x); o.x = (unsigned short)((u + 0x7fffu + ((u >> 16) & 1u)) >> 16);
        u = __float_as_uint(v.y); o.y = (unsigned short)((u + 0x7fffu + ((u >> 16) & 1u)) >> 16);
        u = __float_as_uint(v.z); o.z = (unsigned short)((u + 0x7fffu + ((u >> 16) & 1u)) >> 16);
        u = __float_as_uint(v.w); o.w = (unsigned short)((u + 0x7fffu + ((u >> 16) & 1u)) >> 16);
        ((ushort4*)outp)[i] = o;
    }
}

// ---------------------------------------------------------------------------
// Full-K batched GEMM with fused bias(+tanh). Thread owns 2 j's (j0, j0+64).
// remap=0: out[row][J]; remap=1: out[(nn*TT+t)*VV + j]
// ---------------------------------------------------------------------------
__global__ void gemm_full(const float* __restrict__ Wt, int Jp, int J, int K,
                          const float* __restrict__ X,
                          const float* __restrict__ bias,
                          float* __restrict__ out, int act, int remap) {
    __shared__ float xs[64 * 36];
    int t = blockIdx.y;
    int m0 = t * 32;
    int lane = threadIdx.x & 63;
    int wv = threadIdx.x >> 6;
    int j0 = blockIdx.x * 512 + wv * 128 + lane;
    float acc0[32], acc1[32];
#pragma unroll
    for (int q = 0; q < 32; q++) { acc0[q] = 0.f; acc1[q] = 0.f; }

    for (int kc = 0; kc < K; kc += 64) {
        __syncthreads();
        for (int idx = threadIdx.x; idx < 64 * 32; idx += 256) {
            int n = idx >> 6, k = idx & 63;
            xs[k * 36 + n] = X[(long)(m0 + n) * K + kc + k];
        }
        __syncthreads();
        const float* wpp = Wt + (long)kc * Jp + j0;
#pragma unroll 4
        for (int k = 0; k < 64; k++) {
            float w0 = wpp[(long)k * Jp];
            float w1 = wpp[(long)k * Jp + 64];
            const float4* xv = (const float4*)(xs + k * 36);
#pragma unroll
            for (int q = 0; q < 8; q++) {
                float4 x4 = xv[q];
                acc0[4 * q + 0] += w0 * x4.x;
                acc0[4 * q + 1] += w0 * x4.y;
                acc0[4 * q + 2] += w0 * x4.z;
                acc0[4 * q + 3] += w0 * x4.w;
                acc1[4 * q + 0] += w1 * x4.x;
                acc1[4 * q + 1] += w1 * x4.y;
                acc1[4 * q + 2] += w1 * x4.z;
                acc1[4 * q + 3] += w1 * x4.w;
            }
        }
    }
#pragma unroll
    for (int nn = 0; nn < 32; nn++) {
        long row = remap ? ((long)nn * TT + t) : (long)(m0 + nn);
        float* po = out + row * (remap ? (long)VV : (long)J);
        int ja = j0, jb = j0 + 64;
        if (ja < J) {
            float v = acc0[nn] + bias[ja];
            if (act) v = tanhf(v);
            po[ja] = v;
        }
        if (jb < J) {
            float v = acc1[nn] + bias[jb];
            if (act) v = tanhf(v);
            po[jb] = v;
        }
    }
}

// ---------------------------------------------------------------------------
// Loss: per-(n,t) logsumexp NLL, then mean
// ---------------------------------------------------------------------------
__global__ void loss_rows(const float* __restrict__ out, const int* __restrict__ tokens,
                          float* __restrict__ nll) {
    __shared__ float red[256];
    int row = blockIdx.x;  // n*TT + t
    int n = row / TT, t = row % TT;
    const float* y = out + (long)row * VV;
    int tid = threadIdx.x;
    float m = -1e30f;
    for (int v = tid; v < VV; v += 256) m = fmaxf(m, y[v]);
    red[tid] = m;
    __syncthreads();
    for (int s = 128; s > 0; s >>= 1) {
        if (tid < s) red[tid] = fmaxf(red[tid], red[tid + s]);
        __syncthreads();
    }
    m = red[0];
    __syncthreads();
    float sum = 0.f;
    for (int v = tid; v < VV; v += 256) sum += expf(y[v] - m);
    red[tid] = sum;
    __syncthreads();
    for (int s = 128; s > 0; s >>= 1) {
        if (tid < s) red[tid] += red[tid + s];
        __syncthreads();
    }
    if (tid == 0) {
        int target = (t < TO) ? tokens[n * TO + t] : EOS_ID;
        float lse = m + logf(red[0]);
        nll[row] = lse - y[target];
    }
}

__global__ void loss_final(const float* __restrict__ nll, float* __restrict__ out_loss) {
    __shared__ float red[256];
    int tid = threadIdx.x;
    float s = 0.f;
    for (int i = tid; i < NB * TT; i += 256) s += nll[i];
    red[tid] = s;
    __syncthreads();
    for (int k = 128; k > 0; k >>= 1) {
        if (tid < k) red[tid] += red[tid + k];
        __syncthreads();
    }
    if (tid == 0) *out_loss = red[0] / (float)(NB * TT);
}

// ---------------------------------------------------------------------------
extern "C" void kernel_launch(void* const* d_in, const int* in_sizes, int n_in,
                              void* d_out, int out_size, void* d_ws, size_t ws_size,
                              hipStream_t stream) {
    const int* padded   = (const int*)d_in[0];
    const float* enc    = (const float*)d_in[1];
    const float* emb    = (const float*)d_in[2];
    const float* W_ih0  = (const float*)d_in[3];
    const float* W_hh0  = (const float*)d_in[4];
    const float* b_ih0  = (const float*)d_in[5];
    const float* b_hh0  = (const float*)d_in[6];
    const float* W_ih_r = (const float*)d_in[7];
    const float* W_hh_r = (const float*)d_in[8];
    const float* b_ih_r = (const float*)d_in[9];
    const float* b_hh_r = (const float*)d_in[10];
    const float* W1     = (const float*)d_in[11];
    const float* b1     = (const float*)d_in[12];
    const float* W2     = (const float*)d_in[13];
    const float* b2     = (const float*)d_in[14];
    float* out = (float*)d_out;
    float* ws  = (float*)d_ws;

    // workspace layout (floats), ~65.8 MB total
    float* Wt0  = ws;                        // [1536][2048] k-major, col-permuted
    float* Wt1  = Wt0 + 1536 * 2048;         // [1024][2048]
    float* Wt2  = Wt1 + 1024 * 2048;         // [1024][2048]
    float* Wm1  = Wt2 + 1024 * 2048;         // [1024 k][512 j]
    float* R    = Wm1 + 1024 * 512;          // decode: encbf | tail: Wm2+y1all
    float* hbuf = R + 6307840;               // [2][3][32][512] ping-pong h
    float* attc = hbuf + 2 * 3 * NB * HH;    // [32][512]
    float* scor = attc + NB * HH;            // [32][512]
    float* mlpin= scor + NB * TI;            // [65][32][1024]
    float* nll  = mlpin + (long)TT * NB * 1024;  // [2080]
    int*   cnt  = (int*)(nll + 2112);        // 8 group counters, 256B apart
    unsigned short* encb = (unsigned short*)R;       // decode-phase alias
    float* Wm2  = R;                                 // tail alias [512][10240]
    float* y1all= R + 5242880;                       // tail alias [2080][512]

    // init: zero h (both parities) + attc + scor, and group counters
    hipMemsetAsync(hbuf, 0, (size_t)(2 * 3 * NB * HH + 2 * NB * HH) * sizeof(float), stream);
    hipMemsetAsync(cnt, 0, 2048, stream);

    // prep: permuted k-major weight transposes + enc->bf16
    transpose_cat<<<1024, 256, 0, stream>>>(W1, 1024, nullptr, 0, 512, 512, Wm1);
    transpose_lstm<<<2048, 256, 0, stream>>>(W_ih0, 1024, W_hh0, Wt0);
    transpose_lstm<<<2048, 256, 0, stream>>>(W_ih_r, 512, W_hh_r, Wt1);
    transpose_lstm<<<2048, 256, 0, stream>>>(W_ih_r + 2048 * 512, 512,
                                             W_hh_r + 2048 * 512, Wt2);
    enc_to_bf16<<<2048, 256, 0, stream>>>(enc, encb, (long)NB * TI * HH / 4);

    // persistent recurrence (8 independent groups, group barriers only)
    decode_loop<<<NBLK, 256, 0, stream>>>(Wt0, Wt1, Wt2, emb, padded, encb,
                                          b_ih0, b_hh0, b_ih_r, b_hh_r,
                                          hbuf, attc, scor, mlpin, cnt);

    // deferred MLP over all 2080 rows
    transpose_cat<<<2048, 256, 0, stream>>>(W2, 512, nullptr, 0, VV, 10240, Wm2);
    gemm_full<<<dim3(1, TT), 256, 0, stream>>>(Wm1, 512, 512, 1024, mlpin, b1,
                                               y1all, 1, 0);
    gemm_full<<<dim3(20, TT), 256, 0, stream>>>(Wm2, 10240, VV, 512, y1all, b2,
                                                out, 0, 1);
    loss_rows<<<NB * TT, 256, 0, stream>>>(out, padded, nll);
    loss_final<<<1, 256, 0, stream>>>(nll, out + (long)NB * TT * VV);
}

// Round 8
// 4467.994 us; speedup vs baseline: 4.5776x; 1.6074x over previous
//
#include <hip/hip_runtime.h>
#include <hip/hip_bf16.h>

// Problem constants
#define NB 32      // batch
#define TO 64      // output tokens
#define TT 65      // decode steps (To+1)
#define TI 512     // encoder time
#define VV 10000   // vocab
#define HH 512     // hidden
#define G4 2048    // 4*H
#define SOS_ID 1
#define EOS_ID 2
#define NBLK 256   // 8 independent groups x 32 blocks
#define GBLK 32    // blocks per group (4 batch rows each)

typedef unsigned uvec4 __attribute__((ext_vector_type(4)));

// ---------------------------------------------------------------------------
// Coherent (agent-scope, cache-bypassing) accessors for cross-block state.
// Read-only data (weights/enc/emb) stays on the normal cached path.
// ---------------------------------------------------------------------------
__device__ __forceinline__ float cload1(const float* p) {
    unsigned v = __hip_atomic_load((const unsigned*)p,
                                   __ATOMIC_RELAXED, __HIP_MEMORY_SCOPE_AGENT);
    return __uint_as_float(v);
}
__device__ __forceinline__ float2 cload2(const float* p) {
    unsigned long long v = __hip_atomic_load((const unsigned long long*)p,
                                             __ATOMIC_RELAXED, __HIP_MEMORY_SCOPE_AGENT);
    float2 r;
    r.x = __uint_as_float((unsigned)(v & 0xffffffffull));
    r.y = __uint_as_float((unsigned)(v >> 32));
    return r;
}
__device__ __forceinline__ void cstore(float* p, float v) {
    __hip_atomic_store((unsigned*)p, __float_as_uint(v),
                       __ATOMIC_RELAXED, __HIP_MEMORY_SCOPE_AGENT);
}

// Fence-free GROUP barrier (32 arrivals on a group-private line).
__device__ __forceinline__ void gbar(int* cnt, int& bt) {
    asm volatile("s_waitcnt vmcnt(0) lgkmcnt(0)" ::: "memory");
    __syncthreads();
    bt += GBLK;
    if (threadIdx.x == 0) {
        __hip_atomic_fetch_add(cnt, 1, __ATOMIC_RELAXED, __HIP_MEMORY_SCOPE_AGENT);
        while (__hip_atomic_load(cnt, __ATOMIC_RELAXED, __HIP_MEMORY_SCOPE_AGENT) < bt)
            __builtin_amdgcn_s_sleep(2);
    }
    __syncthreads();
}

__device__ __forceinline__ float bf2f(unsigned u16) {  // bf16 in low 16 bits
    return __uint_as_float(u16 << 16);
}
__device__ __forceinline__ unsigned f2bf(float f) {    // RNE fp32 -> bf16
    unsigned u = __float_as_uint(f);
    return (u + 0x7fffu + ((u >> 16) & 1u)) >> 16;
}

// ---------------------------------------------------------------------------
// Fused LSTM phase: block = 4 n x 64 cols (slice s), 4-wave k-split.
// xs4[k] = float4 of 4 n's x-values; weights k-major [K][2048] permuted so
// block's columns are s*64..s*64+63 (gate*16+ml).
// ---------------------------------------------------------------------------
template <int KQ>
__device__ __forceinline__ void lstm_phase(
    const float* __restrict__ Wt, const float* __restrict__ bi,
    const float* __restrict__ bh, float* __restrict__ hout,
    float& creg, float* __restrict__ mlprow,
    const float4* xs4, float* sg, int s, int n0, int gn, int gml, int gm) {
    int tid = threadIdx.x;
    int lane = tid & 63, wv = tid >> 6;
    const float* wp = Wt + (long)(wv * KQ) * 2048 + s * 64 + lane;
    const float4* xp = xs4 + wv * KQ;
    float a0 = 0.f, a1 = 0.f, a2 = 0.f, a3 = 0.f;
#pragma unroll 8
    for (int k = 0; k < KQ; k++) {
        float w = wp[(long)k * 2048];
        float4 x = xp[k];
        a0 = fmaf(w, x.x, a0); a1 = fmaf(w, x.y, a1);
        a2 = fmaf(w, x.z, a2); a3 = fmaf(w, x.w, a3);
    }
    float4 r4; r4.x = a0; r4.y = a1; r4.z = a2; r4.w = a3;
    ((float4*)sg)[wv * 64 + lane] = r4;
    __syncthreads();
    if (tid < 64) {
        float ga[4];
#pragma unroll
        for (int q = 0; q < 4; q++) {
            int c = q * 16 + gml;
            ga[q] = sg[c * 4 + gn] + sg[(64 + c) * 4 + gn] +
                    sg[(128 + c) * 4 + gn] + sg[(192 + c) * 4 + gn];
        }
        float gi = ga[0] + bi[gm] + bh[gm];
        float gf = ga[1] + bi[512 + gm] + bh[512 + gm];
        float gg = ga[2] + bi[1024 + gm] + bh[1024 + gm];
        float go = ga[3] + bi[1536 + gm] + bh[1536 + gm];
        float si = 1.f / (1.f + expf(-gi));
        float sf = 1.f / (1.f + expf(-gf));
        float so = 1.f / (1.f + expf(-go));
        float c2 = sf * creg + si * tanhf(gg);
        creg = c2;
        float hv = so * tanhf(c2);
        cstore(&hout[(n0 + gn) * 512 + gm], hv);
        if (mlprow) mlprow[(long)(n0 + gn) * 1024 + gm] = hv;
    }
}

// ---------------------------------------------------------------------------
// Persistent decode: 8 groups x 32 blocks; group owns 4 batch rows.
// enc tile (64 ti x 512 h bf16, 64KB) lives in LDS for the whole kernel.
// 5 group barriers per step.
// ---------------------------------------------------------------------------
__global__ __launch_bounds__(256, 1) void decode_loop(
    const float* __restrict__ Wt0, const float* __restrict__ Wt1,
    const float* __restrict__ Wt2, const float* __restrict__ emb,
    const int* __restrict__ tokens, const float* __restrict__ enc,
    const float* __restrict__ b_ih0, const float* __restrict__ b_hh0,
    const float* __restrict__ b_ih_r, const float* __restrict__ b_hh_r,
    float* __restrict__ hbuf, float* __restrict__ attc,
    float* __restrict__ scor, float* __restrict__ mlpin, int* cnt) {
    __shared__ float4 xs4[1536];            // 24KB x-stage / scratch
    __shared__ float sg[1024];              // 4KB gate partials
    __shared__ unsigned short enct[32768];  // 64KB swizzled enc tile
    float* smem = (float*)xs4;

    int tid = threadIdx.x, b = blockIdx.x;
    int g = b >> 5, s = b & 31;             // slice s -> XCD s%8 (== b%8)
    int* mycnt = cnt + g * 64;
    int bt = 0;
    int n0 = g * 4;
    int gn = tid >> 4, gml = tid & 15;      // gating identity (tid<64)
    int gm = s * 16 + gml;
    int na = n0 + (s >> 3), tiq = s & 7;    // attention role: n, ti-tile
    float c0r = 0.f, c1r = 0.f, c2r = 0.f;

    // ---- one-time: load + bf16-convert + swizzle enc tile [64 ti][512 h]
    {
        int tl = tid >> 2;
        int gb = (tid & 3) * 16;
        const float* ebase = enc + ((long)na * TI + tiq * 64 + tl) * HH;
#pragma unroll 4
        for (int q = 0; q < 16; q++) {
            int gg = gb + q;
            const float* ep = ebase + gg * 8;
            float4 lo = *(const float4*)ep;
            float4 hi = *(const float4*)(ep + 4);
            uvec4 pk;
            pk.x = f2bf(lo.x) | (f2bf(lo.y) << 16);
            pk.y = f2bf(lo.z) | (f2bf(lo.w) << 16);
            pk.z = f2bf(hi.x) | (f2bf(hi.y) << 16);
            pk.w = f2bf(hi.z) | (f2bf(hi.w) << 16);
            *(uvec4*)(enct + tl * 512 + (gg ^ (tl & 7)) * 8) = pk;
        }
    }
    __syncthreads();

    for (int t = 0; t < TT; t++) {
        int rp = t & 1;
        float* hOld = hbuf + rp * 3 * NB * HH;
        float* hNew = hbuf + (rp ^ 1) * 3 * NB * HH;
        float* h0r = hOld;
        float* h1r = hOld + NB * HH;
        float* h2r = hOld + 2 * NB * HH;
        float* h0w = hNew;
        float* h1w = hNew + NB * HH;
        float* h2w = hNew + 2 * NB * HH;

        // ===== P1: L0 LSTM, x=[emb|attc|h0r], K=1536 =====
        {
            int r0 = (t == 0) ? SOS_ID : tokens[(n0 + 0) * TO + t - 1];
            int r1 = (t == 0) ? SOS_ID : tokens[(n0 + 1) * TO + t - 1];
            int r2 = (t == 0) ? SOS_ID : tokens[(n0 + 2) * TO + t - 1];
            int r3 = (t == 0) ? SOS_ID : tokens[(n0 + 3) * TO + t - 1];
#pragma unroll
            for (int j = 0; j < 6; j++) {
                int k = tid + j * 256;
                float4 v;
                if (k < 512) {
                    v.x = emb[(long)r0 * 512 + k];
                    v.y = emb[(long)r1 * 512 + k];
                    v.z = emb[(long)r2 * 512 + k];
                    v.w = emb[(long)r3 * 512 + k];
                } else if (k < 1024) {
                    int kk = k - 512;
                    v.x = cload1(attc + (n0 + 0) * 512 + kk);
                    v.y = cload1(attc + (n0 + 1) * 512 + kk);
                    v.z = cload1(attc + (n0 + 2) * 512 + kk);
                    v.w = cload1(attc + (n0 + 3) * 512 + kk);
                    if (t && ((kk >> 4) == s)) {  // exactly-one-block writer
                        float* mp = mlpin + ((long)(t - 1) * NB + n0) * 1024 + 512 + kk;
                        mp[0] = v.x; mp[1024] = v.y; mp[2048] = v.z; mp[3072] = v.w;
                    }
                } else {
                    int kk = k - 1024;
                    v.x = cload1(h0r + (n0 + 0) * 512 + kk);
                    v.y = cload1(h0r + (n0 + 1) * 512 + kk);
                    v.z = cload1(h0r + (n0 + 2) * 512 + kk);
                    v.w = cload1(h0r + (n0 + 3) * 512 + kk);
                }
                xs4[k] = v;
            }
        }
        __syncthreads();
        lstm_phase<384>(Wt0, b_ih0, b_hh0, h0w, c0r, nullptr,
                        xs4, sg, s, n0, gn, gml, gm);
        gbar(mycnt, bt);

        // ===== P2: L1 LSTM, x=[h0w|h1r], K=1024; also zero attc =====
        if (tid < 64) cstore(&attc[n0 * 512 + s * 64 + tid], 0.f);
#pragma unroll
        for (int j = 0; j < 4; j++) {
            int k = tid + j * 256;
            const float* base = (k < 512) ? h0w : (h1r - 512);
            float4 v;
            v.x = cload1(base + (n0 + 0) * 512 + k);
            v.y = cload1(base + (n0 + 1) * 512 + k);
            v.z = cload1(base + (n0 + 2) * 512 + k);
            v.w = cload1(base + (n0 + 3) * 512 + k);
            xs4[k] = v;
        }
        __syncthreads();
        lstm_phase<256>(Wt1, b_ih_r, b_hh_r, h1w, c1r, nullptr,
                        xs4, sg, s, n0, gn, gml, gm);
        gbar(mycnt, bt);

        // ===== P3: L2 LSTM, x=[h1w|h2r], K=1024 (h2' -> mlpin h-half) =====
#pragma unroll
        for (int j = 0; j < 4; j++) {
            int k = tid + j * 256;
            const float* base = (k < 512) ? h1w : (h2r - 512);
            float4 v;
            v.x = cload1(base + (n0 + 0) * 512 + k);
            v.y = cload1(base + (n0 + 1) * 512 + k);
            v.z = cload1(base + (n0 + 2) * 512 + k);
            v.w = cload1(base + (n0 + 3) * 512 + k);
            xs4[k] = v;
        }
        __syncthreads();
        lstm_phase<256>(Wt2, b_ih_r + G4, b_hh_r + G4, h2w, c2r,
                        mlpin + (long)t * NB * 1024,
                        xs4, sg, s, n0, gn, gml, gm);
        gbar(mycnt, bt);

        // ===== P4: scores for tile (na, tiq) from LDS enc =====
        {
            float2 v = cload2(h2w + na * 512 + tid * 2);
            smem[tid * 2] = v.x; smem[tid * 2 + 1] = v.y;
        }
        __syncthreads();
        {
            int tl = tid & 63, kh = tid >> 6;
            float acc = 0.f;
#pragma unroll 4
            for (int q = 0; q < 16; q++) {
                int gg = kh * 16 + q;
                uvec4 e = *(const uvec4*)(enct + tl * 512 + ((gg ^ (tl & 7)) * 8));
                const float* hp = smem + gg * 8;
                acc += bf2f(e.x & 0xffffu) * hp[0] + bf2f(e.x >> 16) * hp[1]
                     + bf2f(e.y & 0xffffu) * hp[2] + bf2f(e.y >> 16) * hp[3]
                     + bf2f(e.z & 0xffffu) * hp[4] + bf2f(e.z >> 16) * hp[5]
                     + bf2f(e.w & 0xffffu) * hp[6] + bf2f(e.w >> 16) * hp[7];
            }
            float* sred = smem + 512;
            sred[tid] = acc;
            __syncthreads();
            if (tid < 64) {
                float sv = sred[tid] + sred[tid + 64] + sred[tid + 128] + sred[tid + 192];
                cstore(&scor[na * 512 + tiq * 64 + tid], sv);
            }
        }
        gbar(mycnt, bt);

        // ===== P5: softmax (full row) + ti-partial apply -> atomicAdd attc ===
        {
            float* sw = smem;          // 512 weights
            float* rr = smem + 512;    // 256 reduce
            {
                float2 v = cload2(scor + na * 512 + tid * 2);
                sw[tid * 2] = v.x; sw[tid * 2 + 1] = v.y;
            }
            __syncthreads();
            float s0 = sw[tid], s1 = sw[tid + 256];
            rr[tid] = fmaxf(s0, s1);
            __syncthreads();
            for (int st = 128; st > 0; st >>= 1) {
                if (tid < st) rr[tid] = fmaxf(rr[tid], rr[tid + st]);
                __syncthreads();
            }
            float mx = rr[0];
            __syncthreads();
            float e0 = expf(s0 - mx), e1 = expf(s1 - mx);
            rr[tid] = e0 + e1;
            __syncthreads();
            for (int st = 128; st > 0; st >>= 1) {
                if (tid < st) rr[tid] += rr[tid + st];
                __syncthreads();
            }
            float inv = 1.f / rr[0];
            __syncthreads();
            sw[tid] = e0 * inv; sw[tid + 256] = e1 * inv;
            __syncthreads();
            int h0 = tid * 2;
            int gb2 = h0 >> 3, wrd = h0 & 7;
            const float* wrow = sw + tiq * 64;
            float a0 = 0.f, a1 = 0.f;
#pragma unroll 8
            for (int tl = 0; tl < 64; tl++) {
                unsigned u = *(const unsigned*)(enct + tl * 512 +
                                                ((gb2 ^ (tl & 7)) * 8) + wrd);
                float w = wrow[tl];
                a0 = fmaf(w, bf2f(u & 0xffffu), a0);
                a1 = fmaf(w, bf2f(u >> 16), a1);
            }
            atomicAdd(&attc[na * 512 + h0], a0);
            atomicAdd(&attc[na * 512 + h0 + 1], a1);
        }
        gbar(mycnt, bt);
    }

    // epilogue: mlpin[TT-1] att-half (never consumed by a next P1)
    if (tid < 64) {
        int h = tiq * 64 + tid;
        mlpin[((long)(TT - 1) * NB + na) * 1024 + 512 + h] =
            cload1(attc + na * 512 + h);
    }
}

// ---------------------------------------------------------------------------
// LSTM weight transpose with slice-permuted columns:
// Wt[k][c], c = s*64 + gate*16 + ml  <->  j = gate*512 + s*16 + ml
// ---------------------------------------------------------------------------
__global__ void transpose_lstm(const float* __restrict__ Wih, int KA,
                               const float* __restrict__ Whh,
                               float* __restrict__ Wt) {
    long total = (long)(KA + 512) * 2048;
    for (long idx = (long)blockIdx.x * 256 + threadIdx.x; idx < total;
         idx += (long)gridDim.x * 256) {
        int c = (int)(idx % 2048);
        int k = (int)(idx / 2048);
        int sI = c >> 6, r = c & 63, gg = r >> 4, ml = r & 15;
        int j = gg * 512 + sI * 16 + ml;
        Wt[idx] = (k < KA) ? Wih[(long)j * KA + k] : Whh[(long)j * 512 + (k - KA)];
    }
}

// Plain transpose for tail GEMMs: Wt[k][j] = A[j][k], zero-padded to Jp
__global__ void transpose_cat(const float* __restrict__ A, int KA,
                              const float* __restrict__ B, int KB,
                              int J, int Jp, float* __restrict__ Wt) {
    int K = KA + KB;
    long total = (long)K * Jp;
    for (long idx = (long)blockIdx.x * 256 + threadIdx.x; idx < total;
         idx += (long)gridDim.x * 256) {
        int j = (int)(idx % Jp);
        int k = (int)(idx / Jp);
        float v = 0.f;
        if (j < J) v = (k < KA) ? A[(long)j * KA + k] : B[(long)j * KB + (k - KA)];
        Wt[idx] = v;
    }
}

// ---------------------------------------------------------------------------
// Full-K batched GEMM with fused bias(+tanh). Thread owns 2 j's (j0, j0+64).
// remap=0: out[row][J]; remap=1: out[(nn*TT+t)*VV + j]
// ---------------------------------------------------------------------------
__global__ void gemm_full(const float* __restrict__ Wt, int Jp, int J, int K,
                          const float* __restrict__ X,
                          const float* __restrict__ bias,
                          float* __restrict__ out, int act, int remap) {
    __shared__ float xs[64 * 36];
    int t = blockIdx.y;
    int m0 = t * 32;
    int lane = threadIdx.x & 63;
    int wv = threadIdx.x >> 6;
    int j0 = blockIdx.x * 512 + wv * 128 + lane;
    float acc0[32], acc1[32];
#pragma unroll
    for (int q = 0; q < 32; q++) { acc0[q] = 0.f; acc1[q] = 0.f; }

    for (int kc = 0; kc < K; kc += 64) {
        __syncthreads();
        for (int idx = threadIdx.x; idx < 64 * 32; idx += 256) {
            int n = idx >> 6, k = idx & 63;
            xs[k * 36 + n] = X[(long)(m0 + n) * K + kc + k];
        }
        __syncthreads();
        const float* wpp = Wt + (long)kc * Jp + j0;
#pragma unroll 4
        for (int k = 0; k < 64; k++) {
            float w0 = wpp[(long)k * Jp];
            float w1 = wpp[(long)k * Jp + 64];
            const float4* xv = (const float4*)(xs + k * 36);
#pragma unroll
            for (int q = 0; q < 8; q++) {
                float4 x4 = xv[q];
                acc0[4 * q + 0] += w0 * x4.x;
                acc0[4 * q + 1] += w0 * x4.y;
                acc0[4 * q + 2] += w0 * x4.z;
                acc0[4 * q + 3] += w0 * x4.w;
                acc1[4 * q + 0] += w1 * x4.x;
                acc1[4 * q + 1] += w1 * x4.y;
                acc1[4 * q + 2] += w1 * x4.z;
                acc1[4 * q + 3] += w1 * x4.w;
            }
        }
    }
#pragma unroll
    for (int nn = 0; nn < 32; nn++) {
        long row = remap ? ((long)nn * TT + t) : (long)(m0 + nn);
        float* po = out + row * (remap ? (long)VV : (long)J);
        int ja = j0, jb = j0 + 64;
        if (ja < J) {
            float v = acc0[nn] + bias[ja];
            if (act) v = tanhf(v);
            po[ja] = v;
        }
        if (jb < J) {
            float v = acc1[nn] + bias[jb];
            if (act) v = tanhf(v);
            po[jb] = v;
        }
    }
}

// ---------------------------------------------------------------------------
// Loss: per-(n,t) logsumexp NLL, then mean
// ---------------------------------------------------------------------------
__global__ void loss_rows(const float* __restrict__ out, const int* __restrict__ tokens,
                          float* __restrict__ nll) {
    __shared__ float red[256];
    int row = blockIdx.x;  // n*TT + t
    int n = row / TT, t = row % TT;
    const float* y = out + (long)row * VV;
    int tid = threadIdx.x;
    float m = -1e30f;
    for (int v = tid; v < VV; v += 256) m = fmaxf(m, y[v]);
    red[tid] = m;
    __syncthreads();
    for (int s = 128; s > 0; s >>= 1) {
        if (tid < s) red[tid] = fmaxf(red[tid], red[tid + s]);
        __syncthreads();
    }
    m = red[0];
    __syncthreads();
    float sum = 0.f;
    for (int v = tid; v < VV; v += 256) sum += expf(y[v] - m);
    red[tid] = sum;
    __syncthreads();
    for (int s = 128; s > 0; s >>= 1) {
        if (tid < s) red[tid] += red[tid + s];
        __syncthreads();
    }
    if (tid == 0) {
        int target = (t < TO) ? tokens[n * TO + t] : EOS_ID;
        float lse = m + logf(red[0]);
        nll[row] = lse - y[target];
    }
}

__global__ void loss_final(const float* __restrict__ nll, float* __restrict__ out_loss) {
    __shared__ float red[256];
    int tid = threadIdx.x;
    float s = 0.f;
    for (int i = tid; i < NB * TT; i += 256) s += nll[i];
    red[tid] = s;
    __syncthreads();
    for (int k = 128; k > 0; k >>= 1) {
        if (tid < k) red[tid] += red[tid + k];
        __syncthreads();
    }
    if (tid == 0) *out_loss = red[0] / (float)(NB * TT);
}

// ---------------------------------------------------------------------------
extern "C" void kernel_launch(void* const* d_in, const int* in_sizes, int n_in,
                              void* d_out, int out_size, void* d_ws, size_t ws_size,
                              hipStream_t stream) {
    const int* padded   = (const int*)d_in[0];
    const float* enc    = (const float*)d_in[1];
    const float* emb    = (const float*)d_in[2];
    const float* W_ih0  = (const float*)d_in[3];
    const float* W_hh0  = (const float*)d_in[4];
    const float* b_ih0  = (const float*)d_in[5];
    const float* b_hh0  = (const float*)d_in[6];
    const float* W_ih_r = (const float*)d_in[7];
    const float* W_hh_r = (const float*)d_in[8];
    const float* b_ih_r = (const float*)d_in[9];
    const float* b_hh_r = (const float*)d_in[10];
    const float* W1     = (const float*)d_in[11];
    const float* b1     = (const float*)d_in[12];
    const float* W2     = (const float*)d_in[13];
    const float* b2     = (const float*)d_in[14];
    float* out = (float*)d_out;
    float* ws  = (float*)d_ws;

    // workspace layout (floats)
    float* Wt0  = ws;                        // [1536][2048] k-major, col-permuted
    float* Wt1  = Wt0 + 1536 * 2048;         // [1024][2048]
    float* Wt2  = Wt1 + 1024 * 2048;         // [1024][2048]
    float* Wm1  = Wt2 + 1024 * 2048;         // [1024 k][512 j]
    float* R    = Wm1 + 1024 * 512;          // tail: Wm2 + y1all
    float* hbuf = R + 6307840;               // [2][3][32][512] ping-pong h
    float* attc = hbuf + 2 * 3 * NB * HH;    // [32][512]
    float* scor = attc + NB * HH;            // [32][512]
    float* mlpin= scor + NB * TI;            // [65][32][1024]
    float* nll  = mlpin + (long)TT * NB * 1024;  // [2080]
    int*   cnt  = (int*)(nll + 2112);        // 8 group counters, 256B apart
    float* Wm2  = R;                                 // tail alias [512][10240]
    float* y1all= R + 5242880;                       // tail alias [2080][512]

    // init: zero h (both parities) + attc + scor, and group counters
    hipMemsetAsync(hbuf, 0, (size_t)(2 * 3 * NB * HH + 2 * NB * HH) * sizeof(float), stream);
    hipMemsetAsync(cnt, 0, 2048, stream);

    // prep: permuted k-major weight transposes
    transpose_cat<<<1024, 256, 0, stream>>>(W1, 1024, nullptr, 0, 512, 512, Wm1);
    transpose_lstm<<<2048, 256, 0, stream>>>(W_ih0, 1024, W_hh0, Wt0);
    transpose_lstm<<<2048, 256, 0, stream>>>(W_ih_r, 512, W_hh_r, Wt1);
    transpose_lstm<<<2048, 256, 0, stream>>>(W_ih_r + 2048 * 512, 512,
                                             W_hh_r + 2048 * 512, Wt2);

    // persistent recurrence (8 independent groups, group barriers only)
    decode_loop<<<NBLK, 256, 0, stream>>>(Wt0, Wt1, Wt2, emb, padded, enc,
                                          b_ih0, b_hh0, b_ih_r, b_hh_r,
                                          hbuf, attc, scor, mlpin, cnt);

    // deferred MLP over all 2080 rows
    transpose_cat<<<2048, 256, 0, stream>>>(W2, 512, nullptr, 0, VV, 10240, Wm2);
    gemm_full<<<dim3(1, TT), 256, 0, stream>>>(Wm1, 512, 512, 1024, mlpin, b1,
                                               y1all, 1, 0);
    gemm_full<<<dim3(20, TT), 256, 0, stream>>>(Wm2, 10240, VV, 512, y1all, b2,
                                                out, 0, 1);
    loss_rows<<<NB * TT, 256, 0, stream>>>(out, padded, nll);
    loss_final<<<1, 256, 0, stream>>>(nll, out + (long)NB * TT * VV);
}

// Round 9
// 3004.408 us; speedup vs baseline: 6.8076x; 1.4871x over previous
//
#include <hip/hip_runtime.h>
#include <hip/hip_bf16.h>

// Problem constants
#define NB 32
#define TO 64
#define TT 65
#define TI 512
#define VV 10000
#define HH 512
#define G4 2048
#define SOS_ID 1
#define EOS_ID 2
#define NBLK 256
#define GBLK 32

typedef unsigned uvec4 __attribute__((ext_vector_type(4)));

__device__ __forceinline__ float cload1(const float* p) {
    unsigned v = __hip_atomic_load((const unsigned*)p,
                                   __ATOMIC_RELAXED, __HIP_MEMORY_SCOPE_AGENT);
    return __uint_as_float(v);
}
__device__ __forceinline__ float2 cload2(const float* p) {
    unsigned long long v = __hip_atomic_load((const unsigned long long*)p,
                                             __ATOMIC_RELAXED, __HIP_MEMORY_SCOPE_AGENT);
    float2 r;
    r.x = __uint_as_float((unsigned)(v & 0xffffffffull));
    r.y = __uint_as_float((unsigned)(v >> 32));
    return r;
}
__device__ __forceinline__ void cstore(float* p, float v) {
    __hip_atomic_store((unsigned*)p, __float_as_uint(v),
                       __ATOMIC_RELAXED, __HIP_MEMORY_SCOPE_AGENT);
}

// Flag-array group barrier: arrival = private-line store; wave-0 lanes poll.
__device__ __forceinline__ void gbar(int* flags, int g, int s, int& epoch) {
    asm volatile("s_waitcnt vmcnt(0) lgkmcnt(0)" ::: "memory");
    __syncthreads();
    epoch++;
    int tid = threadIdx.x;
    if (tid == 0)
        __hip_atomic_store(&flags[(g * 32 + s) * 16], epoch,
                           __ATOMIC_RELAXED, __HIP_MEMORY_SCOPE_AGENT);
    if (tid < 32) {
        for (;;) {
            int v = __hip_atomic_load(&flags[(g * 32 + tid) * 16],
                                      __ATOMIC_RELAXED, __HIP_MEMORY_SCOPE_AGENT);
            unsigned long long b = __ballot(v >= epoch);
            if ((b & 0xffffffffull) == 0xffffffffull) break;
            __builtin_amdgcn_s_sleep(1);
        }
    }
    __syncthreads();
}

__device__ __forceinline__ float bf2f(unsigned u16) {
    return __uint_as_float(u16 << 16);
}
__device__ __forceinline__ unsigned f2bf(float f) {
    unsigned u = __float_as_uint(f);
    return (u + 0x7fffu + ((u >> 16) & 1u)) >> 16;
}

// Fused LSTM phase: 8-wave k-split, bf16 k-pair weights.
template <int KQ2>  // 96 (L0) or 64 (L1,L2)
__device__ __forceinline__ void lstm_phase(
    const unsigned* __restrict__ Wtb, const float* __restrict__ bi,
    const float* __restrict__ bh, float* __restrict__ hout,
    float& creg, float* __restrict__ mlprow,
    const float4* xs4, float* sg, int s, int n0, int gn, int gml, int gm) {
    int tid = threadIdx.x;
    int lane = tid & 63, wv = tid >> 6;
    const unsigned* wp = Wtb + (long)(wv * KQ2) * 2048 + s * 64 + lane;
    const float4* xp = xs4 + wv * KQ2 * 2;
    float a0 = 0.f, a1 = 0.f, a2 = 0.f, a3 = 0.f;
#pragma unroll 8
    for (int k = 0; k < KQ2; k++) {
        unsigned u = wp[(long)k * 2048];
        float w0 = bf2f(u & 0xffffu), w1 = bf2f(u >> 16);
        float4 x0 = xp[2 * k], x1 = xp[2 * k + 1];
        a0 = fmaf(w0, x0.x, a0); a1 = fmaf(w0, x0.y, a1);
        a2 = fmaf(w0, x0.z, a2); a3 = fmaf(w0, x0.w, a3);
        a0 = fmaf(w1, x1.x, a0); a1 = fmaf(w1, x1.y, a1);
        a2 = fmaf(w1, x1.z, a2); a3 = fmaf(w1, x1.w, a3);
    }
    float4 r4; r4.x = a0; r4.y = a1; r4.z = a2; r4.w = a3;
    ((float4*)sg)[wv * 64 + lane] = r4;
    __syncthreads();
    if (tid < 64) {
        float ga[4];
#pragma unroll
        for (int q = 0; q < 4; q++) {
            int c = q * 16 + gml;
            float sum = 0.f;
#pragma unroll
            for (int w = 0; w < 8; w++) sum += sg[(w * 64 + c) * 4 + gn];
            ga[q] = sum;
        }
        float gi = ga[0] + bi[gm] + bh[gm];
        float gf = ga[1] + bi[512 + gm] + bh[512 + gm];
        float gg = ga[2] + bi[1024 + gm] + bh[1024 + gm];
        float go = ga[3] + bi[1536 + gm] + bh[1536 + gm];
        float si = 1.f / (1.f + expf(-gi));
        float sf = 1.f / (1.f + expf(-gf));
        float so = 1.f / (1.f + expf(-go));
        float c2 = sf * creg + si * tanhf(gg);
        creg = c2;
        float hv = so * tanhf(c2);
        cstore(&hout[(n0 + gn) * 512 + gm], hv);
        if (mlprow) mlprow[(long)(n0 + gn) * 1024 + gm] = hv;
    }
}

__global__ __launch_bounds__(512, 1) void decode_loop(
    const unsigned* __restrict__ Wtb0, const unsigned* __restrict__ Wtb1,
    const unsigned* __restrict__ Wtb2, const float* __restrict__ emb,
    const int* __restrict__ tokens, const float* __restrict__ enc,
    const float* __restrict__ b_ih0, const float* __restrict__ b_hh0,
    const float* __restrict__ b_ih_r, const float* __restrict__ b_hh_r,
    float* __restrict__ hbuf, float* __restrict__ attc,
    float* __restrict__ scor, float* __restrict__ mlpin, int* flags) {
    __shared__ float4 xs4[1536];
    __shared__ float sg[2048];
    __shared__ unsigned short enct[32768];
    float* xsf = (float*)xs4;

    int tid = threadIdx.x, b = blockIdx.x;
    int g = b >> 5, s = b & 31;
    int epoch = 0;
    int n0 = g * 4;
    int lane = tid & 63;
    int gn = tid >> 4, gml = tid & 15;
    int gm = s * 16 + gml;
    int na = n0 + (s >> 3), tiq = s & 7;
    float c0r = 0.f, c1r = 0.f, c2r = 0.f;

    {   // one-time enc tile -> LDS (bf16, swizzled)
        int tl = tid >> 3;
        int gb = (tid & 7) * 8;
        const float* ebase = enc + ((long)na * TI + tiq * 64 + tl) * HH;
#pragma unroll
        for (int q = 0; q < 8; q++) {
            int gg = gb + q;
            const float* ep = ebase + gg * 8;
            float4 lo = *(const float4*)ep;
            float4 hi = *(const float4*)(ep + 4);
            uvec4 pk;
            pk.x = f2bf(lo.x) | (f2bf(lo.y) << 16);
            pk.y = f2bf(lo.z) | (f2bf(lo.w) << 16);
            pk.z = f2bf(hi.x) | (f2bf(hi.y) << 16);
            pk.w = f2bf(hi.z) | (f2bf(hi.w) << 16);
            *(uvec4*)(enct + tl * 512 + (gg ^ (tl & 7)) * 8) = pk;
        }
    }
    __syncthreads();

    for (int t = 0; t < TT; t++) {
        int rp = t & 1;
        float* hOld = hbuf + rp * 3 * NB * HH;
        float* hNew = hbuf + (rp ^ 1) * 3 * NB * HH;
        float* h0r = hOld;
        float* h1r = hOld + NB * HH;
        float* h2r = hOld + 2 * NB * HH;
        float* h0w = hNew;
        float* h1w = hNew + NB * HH;
        float* h2w = hNew + 2 * NB * HH;

        // ===== P1: L0 LSTM =====
        {
            int r0 = (t == 0) ? SOS_ID : tokens[(n0 + 0) * TO + t - 1];
            int r1 = (t == 0) ? SOS_ID : tokens[(n0 + 1) * TO + t - 1];
            int r2 = (t == 0) ? SOS_ID : tokens[(n0 + 2) * TO + t - 1];
            int r3 = (t == 0) ? SOS_ID : tokens[(n0 + 3) * TO + t - 1];
#pragma unroll
            for (int j = 0; j < 2; j++) {
                int p = tid + j * 512;
                if (p < 768) {
                    int k = p * 2;
                    float2 va, vb, vc, vd;
                    if (k < 512) {
                        va = *(const float2*)(emb + (long)r0 * 512 + k);
                        vb = *(const float2*)(emb + (long)r1 * 512 + k);
                        vc = *(const float2*)(emb + (long)r2 * 512 + k);
                        vd = *(const float2*)(emb + (long)r3 * 512 + k);
                    } else if (k < 1024) {
                        int kk = k - 512;
                        va = cload2(attc + (n0 + 0) * 512 + kk);
                        vb = cload2(attc + (n0 + 1) * 512 + kk);
                        vc = cload2(attc + (n0 + 2) * 512 + kk);
                        vd = cload2(attc + (n0 + 3) * 512 + kk);
                        if (t && ((kk >> 4) == s)) {
                            float* mp = mlpin + ((long)(t - 1) * NB + n0) * 1024 + 512 + kk;
                            mp[0] = va.x; mp[1] = va.y;
                            mp[1024] = vb.x; mp[1025] = vb.y;
                            mp[2048] = vc.x; mp[2049] = vc.y;
                            mp[3072] = vd.x; mp[3073] = vd.y;
                        }
                    } else {
                        int kk = k - 1024;
                        va = cload2(h0r + (n0 + 0) * 512 + kk);
                        vb = cload2(h0r + (n0 + 1) * 512 + kk);
                        vc = cload2(h0r + (n0 + 2) * 512 + kk);
                        vd = cload2(h0r + (n0 + 3) * 512 + kk);
                    }
                    float4 x0, x1;
                    x0.x = va.x; x0.y = vb.x; x0.z = vc.x; x0.w = vd.x;
                    x1.x = va.y; x1.y = vb.y; x1.z = vc.y; x1.w = vd.y;
                    xs4[k] = x0; xs4[k + 1] = x1;
                }
            }
        }
        __syncthreads();
        lstm_phase<96>(Wtb0, b_ih0, b_hh0, h0w, c0r, nullptr,
                       xs4, sg, s, n0, gn, gml, gm);
        gbar(flags, g, s, epoch);

        // ===== P2: L1 LSTM; zero attc =====
        if (tid < 64) cstore(&attc[n0 * 512 + s * 64 + tid], 0.f);
        {
            int k = tid * 2;
            const float* base = (k < 512) ? h0w : (h1r - 512);
            float2 va = cload2(base + (n0 + 0) * 512 + k);
            float2 vb = cload2(base + (n0 + 1) * 512 + k);
            float2 vc = cload2(base + (n0 + 2) * 512 + k);
            float2 vd = cload2(base + (n0 + 3) * 512 + k);
            float4 x0, x1;
            x0.x = va.x; x0.y = vb.x; x0.z = vc.x; x0.w = vd.x;
            x1.x = va.y; x1.y = vb.y; x1.z = vc.y; x1.w = vd.y;
            xs4[k] = x0; xs4[k + 1] = x1;
        }
        __syncthreads();
        lstm_phase<64>(Wtb1, b_ih_r, b_hh_r, h1w, c1r, nullptr,
                       xs4, sg, s, n0, gn, gml, gm);
        gbar(flags, g, s, epoch);

        // ===== P3: L2 LSTM =====
        {
            int k = tid * 2;
            const float* base = (k < 512) ? h1w : (h2r - 512);
            float2 va = cload2(base + (n0 + 0) * 512 + k);
            float2 vb = cload2(base + (n0 + 1) * 512 + k);
            float2 vc = cload2(base + (n0 + 2) * 512 + k);
            float2 vd = cload2(base + (n0 + 3) * 512 + k);
            float4 x0, x1;
            x0.x = va.x; x0.y = vb.x; x0.z = vc.x; x0.w = vd.x;
            x1.x = va.y; x1.y = vb.y; x1.z = vc.y; x1.w = vd.y;
            xs4[k] = x0; xs4[k + 1] = x1;
        }
        __syncthreads();
        lstm_phase<64>(Wtb2, b_ih_r + G4, b_hh_r + G4, h2w, c2r,
                       mlpin + (long)t * NB * 1024,
                       xs4, sg, s, n0, gn, gml, gm);
        gbar(flags, g, s, epoch);

        // ===== P4: scores =====
        xsf[tid] = cload1(h2w + na * 512 + tid);
        __syncthreads();
        {
            int tl = tid & 63, kh = tid >> 6;
            float acc = 0.f;
#pragma unroll
            for (int q = 0; q < 8; q++) {
                int gg = kh * 8 + q;
                uvec4 e = *(const uvec4*)(enct + tl * 512 + ((gg ^ (tl & 7)) * 8));
                const float* hp = xsf + gg * 8;
                acc += bf2f(e.x & 0xffffu) * hp[0] + bf2f(e.x >> 16) * hp[1]
                     + bf2f(e.y & 0xffffu) * hp[2] + bf2f(e.y >> 16) * hp[3]
                     + bf2f(e.z & 0xffffu) * hp[4] + bf2f(e.z >> 16) * hp[5]
                     + bf2f(e.w & 0xffffu) * hp[6] + bf2f(e.w >> 16) * hp[7];
            }
            sg[tid] = acc;
            __syncthreads();
            if (tid < 64) {
                float sv = 0.f;
#pragma unroll
                for (int w = 0; w < 8; w++) sv += sg[tid + 64 * w];
                cstore(&scor[na * 512 + tiq * 64 + tid], sv);
            }
        }
        gbar(flags, g, s, epoch);

        // ===== P5: softmax + apply =====
        {
            float sv = cload1(scor + na * 512 + tid);
            int wv = tid >> 6;
            float m = sv;
#pragma unroll
            for (int o = 32; o > 0; o >>= 1) m = fmaxf(m, __shfl_xor(m, o));
            if (lane == 0) sg[wv] = m;
            __syncthreads();
            m = fmaxf(fmaxf(fmaxf(sg[0], sg[1]), fmaxf(sg[2], sg[3])),
                      fmaxf(fmaxf(sg[4], sg[5]), fmaxf(sg[6], sg[7])));
            float e = expf(sv - m);
            float ss = e;
#pragma unroll
            for (int o = 32; o > 0; o >>= 1) ss += __shfl_xor(ss, o);
            if (lane == 0) sg[8 + wv] = ss;
            __syncthreads();
            float tot = sg[8] + sg[9] + sg[10] + sg[11] +
                        sg[12] + sg[13] + sg[14] + sg[15];
            float inv = 1.f / tot;
            __syncthreads();
            xsf[tid] = e * inv;
            __syncthreads();

            int hp = (tid & 255) * 2, tis = (tid >> 8) * 32;
            int gb2 = hp >> 3, wrd = hp & 7;
            const float* wrow = xsf + tiq * 64;
            float a0 = 0.f, a1 = 0.f;
#pragma unroll 8
            for (int q = 0; q < 32; q++) {
                int tl = tis + q;
                unsigned u = *(const unsigned*)(enct + tl * 512 +
                                                ((gb2 ^ (tl & 7)) * 8) + wrd);
                float w = wrow[tl];
                a0 = fmaf(w, bf2f(u & 0xffffu), a0);
                a1 = fmaf(w, bf2f(u >> 16), a1);
            }
            float* prt = xsf + 1024;
            prt[(tid >> 8) * 512 + hp] = a0;
            prt[(tid >> 8) * 512 + hp + 1] = a1;
            __syncthreads();
            if (tid < 256) {
                int h = tid * 2;
                atomicAdd(&attc[na * 512 + h], prt[h] + prt[512 + h]);
                atomicAdd(&attc[na * 512 + h + 1], prt[h + 1] + prt[512 + h + 1]);
            }
        }
        gbar(flags, g, s, epoch);
    }

    if (tid < 64) {
        int h = tiq * 64 + tid;
        mlpin[((long)(TT - 1) * NB + na) * 1024 + 512 + h] =
            cload1(attc + na * 512 + h);
    }
}

__global__ void transpose_lstm_bf16(const float* __restrict__ Wih, int KA,
                                    const float* __restrict__ Whh,
                                    unsigned* __restrict__ Wtb) {
    int K = KA + 512;
    long total = (long)(K / 2) * 2048;
    for (long idx = (long)blockIdx.x * 256 + threadIdx.x; idx < total;
         idx += (long)gridDim.x * 256) {
        int c = (int)(idx % 2048);
        int kk2 = (int)(idx / 2048);
        int sI = c >> 6, r = c & 63, gg = r >> 4, ml = r & 15;
        int j = gg * 512 + sI * 16 + ml;
        int k0 = kk2 * 2, k1 = k0 + 1;
        float w0 = (k0 < KA) ? Wih[(long)j * KA + k0] : Whh[(long)j * 512 + (k0 - KA)];
        float w1 = (k1 < KA) ? Wih[(long)j * KA + k1] : Whh[(long)j * 512 + (k1 - KA)];
        Wtb[idx] = f2bf(w0) | (f2bf(w1) << 16);
    }
}

__global__ void transpose_w2_bf16(const float* __restrict__ W2,
                                  unsigned* __restrict__ Wb) {
    long total = (long)512 * 5120;
    for (long idx = (long)blockIdx.x * 256 + threadIdx.x; idx < total;
         idx += (long)gridDim.x * 256) {
        int j = (int)(idx % 5120);
        int k = (int)(idx / 5120);
        float lo = W2[(long)j * 512 + k];
        int j2 = j + 5120;
        float hi = (j2 < VV) ? W2[(long)j2 * 512 + k] : 0.f;
        Wb[idx] = f2bf(lo) | (f2bf(hi) << 16);
    }
}

__global__ void transpose_cat(const float* __restrict__ A, int KA,
                              int J, int Jp, float* __restrict__ Wt) {
    long total = (long)KA * Jp;
    for (long idx = (long)blockIdx.x * 256 + threadIdx.x; idx < total;
         idx += (long)gridDim.x * 256) {
        int j = (int)(idx % Jp);
        int k = (int)(idx / Jp);
        Wt[idx] = (j < J) ? A[(long)j * KA + k] : 0.f;
    }
}

__global__ void gemm_mlp1(const float* __restrict__ Wt,
                          const float* __restrict__ X,
                          const float* __restrict__ bias,
                          float* __restrict__ out) {
    __shared__ float xs[64 * 36];
    int t = blockIdx.y;
    int m0 = t * 32;
    int lane = threadIdx.x & 63;
    int wv = threadIdx.x >> 6;
    int j0 = wv * 128 + lane;
    float acc0[32], acc1[32];
#pragma unroll
    for (int q = 0; q < 32; q++) { acc0[q] = 0.f; acc1[q] = 0.f; }
    for (int kc = 0; kc < 1024; kc += 64) {
        __syncthreads();
        for (int idx = threadIdx.x; idx < 64 * 32; idx += 256) {
            int n = idx >> 6, k = idx & 63;
            xs[k * 36 + n] = X[(long)(m0 + n) * 1024 + kc + k];
        }
        __syncthreads();
        const float* wpp = Wt + (long)kc * 512 + j0;
#pragma unroll 4
        for (int k = 0; k < 64; k++) {
            float w0 = wpp[(long)k * 512];
            float w1 = wpp[(long)k * 512 + 64];
            const float4* xv = (const float4*)(xs + k * 36);
#pragma unroll
            for (int q = 0; q < 8; q++) {
                float4 x4 = xv[q];
                acc0[4 * q + 0] += w0 * x4.x; acc0[4 * q + 1] += w0 * x4.y;
                acc0[4 * q + 2] += w0 * x4.z; acc0[4 * q + 3] += w0 * x4.w;
                acc1[4 * q + 0] += w1 * x4.x; acc1[4 * q + 1] += w1 * x4.y;
                acc1[4 * q + 2] += w1 * x4.z; acc1[4 * q + 3] += w1 * x4.w;
            }
        }
    }
#pragma unroll
    for (int nn = 0; nn < 32; nn++) {
        float* po = out + (long)(m0 + nn) * 512;
        po[j0] = tanhf(acc0[nn] + bias[j0]);
        po[j0 + 64] = tanhf(acc1[nn] + bias[j0 + 64]);
    }
}

// MLP2: bf16 packed (j, j+5120); thread owns dword column j0.
__global__ void gemm_mlp2(const unsigned* __restrict__ Wb,
                          const float* __restrict__ X,
                          const float* __restrict__ bias,
                          float* __restrict__ out) {
    __shared__ float xs[64 * 36];
    int t = blockIdx.y;
    int m0 = t * 32;
    int lane = threadIdx.x & 63;
    int wv = threadIdx.x >> 6;
    int j0 = blockIdx.x * 256 + wv * 64 + lane;   // 0..5119 over grid.x=20
    float acc0[32], acc1[32];
#pragma unroll
    for (int q = 0; q < 32; q++) { acc0[q] = 0.f; acc1[q] = 0.f; }
    for (int kc = 0; kc < 512; kc += 64) {
        __syncthreads();
        for (int idx = threadIdx.x; idx < 64 * 32; idx += 256) {
            int n = idx >> 6, k = idx & 63;
            xs[k * 36 + n] = X[(long)(m0 + n) * 512 + kc + k];
        }
        __syncthreads();
        const unsigned* wpp = Wb + (long)kc * 5120 + j0;
#pragma unroll 4
        for (int k = 0; k < 64; k++) {
            unsigned u = wpp[(long)k * 5120];
            float wlo = bf2f(u & 0xffffu), whi = bf2f(u >> 16);
            const float4* xv = (const float4*)(xs + k * 36);
#pragma unroll
            for (int q = 0; q < 8; q++) {
                float4 x4 = xv[q];
                acc0[4 * q + 0] += wlo * x4.x; acc0[4 * q + 1] += wlo * x4.y;
                acc0[4 * q + 2] += wlo * x4.z; acc0[4 * q + 3] += wlo * x4.w;
                acc1[4 * q + 0] += whi * x4.x; acc1[4 * q + 1] += whi * x4.y;
                acc1[4 * q + 2] += whi * x4.z; acc1[4 * q + 3] += whi * x4.w;
            }
        }
    }
#pragma unroll
    for (int nn = 0; nn < 32; nn++) {
        long row = (long)nn * TT + t;
        float* po = out + row * VV;
        int ja = j0, jb = j0 + 5120;
        po[ja] = acc0[nn] + bias[ja];
        if (jb < VV) po[jb] = acc1[nn] + bias[jb];
    }
}

__global__ void loss_rows(const float* __restrict__ out, const int* __restrict__ tokens,
                          float* __restrict__ nll) {
    __shared__ float red[256];
    int row = blockIdx.x;
    int n = row / TT, t = row % TT;
    const float* y = out + (long)row * VV;
    int tid = threadIdx.x;
    float m = -1e30f;
    for (int v = tid; v < VV; v += 256) m = fmaxf(m, y[v]);
    red[tid] = m;
    __syncthreads();
    for (int s = 128; s > 0; s >>= 1) {
        if (tid < s) red[tid] = fmaxf(red[tid], red[tid + s]);
        __syncthreads();
    }
    m = red[0];
    __syncthreads();
    float sum = 0.f;
    for (int v = tid; v < VV; v += 256) sum += expf(y[v] - m);
    red[tid] = sum;
    __syncthreads();
    for (int s = 128; s > 0; s >>= 1) {
        if (tid < s) red[tid] += red[tid + s];
        __syncthreads();
    }
    if (tid == 0) {
        int target = (t < TO) ? tokens[n * TO + t] : EOS_ID;
        nll[row] = m + logf(red[0]) - y[target];
    }
}

__global__ void loss_final(const float* __restrict__ nll, float* __restrict__ out_loss) {
    __shared__ float red[256];
    int tid = threadIdx.x;
    float s = 0.f;
    for (int i = tid; i < NB * TT; i += 256) s += nll[i];
    red[tid] = s;
    __syncthreads();
    for (int k = 128; k > 0; k >>= 1) {
        if (tid < k) red[tid] += red[tid + k];
        __syncthreads();
    }
    if (tid == 0) *out_loss = red[0] / (float)(NB * TT);
}

extern "C" void kernel_launch(void* const* d_in, const int* in_sizes, int n_in,
                              void* d_out, int out_size, void* d_ws, size_t ws_size,
                              hipStream_t stream) {
    const int* padded   = (const int*)d_in[0];
    const float* enc    = (const float*)d_in[1];
    const float* emb    = (const float*)d_in[2];
    const float* W_ih0  = (const float*)d_in[3];
    const float* W_hh0  = (const float*)d_in[4];
    const float* b_ih0  = (const float*)d_in[5];
    const float* b_hh0  = (const float*)d_in[6];
    const float* W_ih_r = (const float*)d_in[7];
    const float* W_hh_r = (const float*)d_in[8];
    const float* b_ih_r = (const float*)d_in[9];
    const float* b_hh_r = (const float*)d_in[10];
    const float* W1     = (const float*)d_in[11];
    const float* b1     = (const float*)d_in[12];
    const float* W2     = (const float*)d_in[13];
    const float* b2     = (const float*)d_in[14];
    float* out = (float*)d_out;
    float* ws  = (float*)d_ws;

    unsigned* Wtb0 = (unsigned*)ws;              // [768][2048]
    unsigned* Wtb1 = Wtb0 + 768 * 2048;          // [512][2048]
    unsigned* Wtb2 = Wtb1 + 512 * 2048;          // [512][2048]
    unsigned* Wm2b = Wtb2 + 512 * 2048;          // [512][5120]
    float* Wm1  = (float*)(Wm2b + 512 * 5120);   // [1024][512]
    float* hbuf = Wm1 + 1024 * 512;              // [2][3][32][512]
    float* attc = hbuf + 2 * 3 * NB * HH;        // [32][512]
    float* scor = attc + NB * HH;                // [32][512]
    float* mlpin= scor + NB * TI;                // [65][32][1024]
    float* y1all= mlpin + (long)TT * NB * 1024;  // [2080][512]
    float* nll  = y1all + (long)TT * NB * 512;   // [2080]
    int*   flags= (int*)(nll + 2080);            // [8][32][16]

    hipMemsetAsync(hbuf, 0, (size_t)(2 * 3 * NB * HH + 2 * NB * HH) * sizeof(float), stream);
    hipMemsetAsync(flags, 0, 8 * 32 * 16 * sizeof(int), stream);

    transpose_cat<<<1024, 256, 0, stream>>>(W1, 1024, 512, 512, Wm1);
    transpose_lstm_bf16<<<2048, 256, 0, stream>>>(W_ih0, 1024, W_hh0, Wtb0);
    transpose_lstm_bf16<<<2048, 256, 0, stream>>>(W_ih_r, 512, W_hh_r, Wtb1);
    transpose_lstm_bf16<<<2048, 256, 0, stream>>>(W_ih_r + 2048 * 512, 512,
                                                  W_hh_r + 2048 * 512, Wtb2);
    transpose_w2_bf16<<<2048, 256, 0, stream>>>(W2, Wm2b);

    decode_loop<<<NBLK, 512, 0, stream>>>(Wtb0, Wtb1, Wtb2, emb, padded, enc,
                                          b_ih0, b_hh0, b_ih_r, b_hh_r,
                                          hbuf, attc, scor, mlpin, flags);

    gemm_mlp1<<<dim3(1, TT), 256, 0, stream>>>(Wm1, mlpin, b1, y1all);
    gemm_mlp2<<<dim3(20, TT), 256, 0, stream>>>(Wm2b, y1all, b2, out);
    loss_rows<<<NB * TT, 256, 0, stream>>>(out, padded, nll);
    loss_final<<<1, 256, 0, stream>>>(nll, out + (long)NB * TT * VV);
}

// Round 11
// 2416.741 us; speedup vs baseline: 8.4630x; 1.2432x over previous
//
#include <hip/hip_runtime.h>
#include <hip/hip_bf16.h>
#include <hip/hip_fp16.h>

// Problem constants
#define NB 32
#define TO 64
#define TT 65
#define TI 512
#define VV 10000
#define HH 512
#define G4 2048
#define SOS_ID 1
#define EOS_ID 2
#define NBLK 256
#define GBLK 32

typedef unsigned uvec4 __attribute__((ext_vector_type(4)));
typedef unsigned uvec2 __attribute__((ext_vector_type(2)));
typedef _Float16 h2v __attribute__((ext_vector_type(2)));

__device__ __forceinline__ float cload1(const float* p) {
    unsigned v = __hip_atomic_load((const unsigned*)p,
                                   __ATOMIC_RELAXED, __HIP_MEMORY_SCOPE_AGENT);
    return __uint_as_float(v);
}
__device__ __forceinline__ float2 cload2(const float* p) {
    unsigned long long v = __hip_atomic_load((const unsigned long long*)p,
                                             __ATOMIC_RELAXED, __HIP_MEMORY_SCOPE_AGENT);
    float2 r;
    r.x = __uint_as_float((unsigned)(v & 0xffffffffull));
    r.y = __uint_as_float((unsigned)(v >> 32));
    return r;
}
__device__ __forceinline__ void cstore(float* p, float v) {
    __hip_atomic_store((unsigned*)p, __float_as_uint(v),
                       __ATOMIC_RELAXED, __HIP_MEMORY_SCOPE_AGENT);
}

// Flag-array group barrier: arrival = private-line store; wave-0 lanes poll.
__device__ __forceinline__ void gbar(int* flags, int g, int s, int& epoch) {
    asm volatile("s_waitcnt vmcnt(0) lgkmcnt(0)" ::: "memory");
    __syncthreads();
    epoch++;
    int tid = threadIdx.x;
    if (tid == 0)
        __hip_atomic_store(&flags[(g * 32 + s) * 16], epoch,
                           __ATOMIC_RELAXED, __HIP_MEMORY_SCOPE_AGENT);
    if (tid < 32) {
        for (;;) {
            int v = __hip_atomic_load(&flags[(g * 32 + tid) * 16],
                                      __ATOMIC_RELAXED, __HIP_MEMORY_SCOPE_AGENT);
            unsigned long long b = __ballot(v >= epoch);
            if ((b & 0xffffffffull) == 0xffffffffull) break;
            __builtin_amdgcn_s_sleep(1);
        }
    }
    __syncthreads();
}

__device__ __forceinline__ float bf2f(unsigned u16) {
    return __uint_as_float(u16 << 16);
}
__device__ __forceinline__ unsigned f2bf(float f) {
    unsigned u = __float_as_uint(f);
    return (u + 0x7fffu + ((u >> 16) & 1u)) >> 16;
}
__device__ __forceinline__ unsigned packh2(float a, float b) {
    __half2 h = __floats2half2_rn(a, b);
    return *(unsigned*)&h;
}
__device__ __forceinline__ h2v uash2(unsigned u) {
    union { unsigned u; h2v h; } c; c.u = u; return c.h;
}

// ---------------------------------------------------------------------------
// Fused LSTM phase: 16-wave k-split, bf16 quad-packed weights.
// Wtb: [K/4][4096] dwords; column c's quad kq at dwords kq*4096 + c*2 + {0,1}.
// ---------------------------------------------------------------------------
template <int KQ4>  // quads per wave: 24 (L0) or 16 (L1,L2)
__device__ __forceinline__ void lstm_phase(
    const unsigned* __restrict__ Wtb, const float* __restrict__ bi,
    const float* __restrict__ bh, float* __restrict__ hout,
    float& creg, float* __restrict__ mlprow,
    const float4* xs4, float* sg, int s, int n0, int gn, int gml, int gm) {
    int tid = threadIdx.x;
    int lane = tid & 63, wv = tid >> 6;   // wv 0..15
    const uvec2* wp = (const uvec2*)Wtb + (long)(wv * KQ4) * 2048 + (s * 64 + lane);
    const float4* xp = xs4 + wv * KQ4 * 4;
    float a0 = 0.f, a1 = 0.f, a2 = 0.f, a3 = 0.f;
#pragma unroll 4
    for (int kq = 0; kq < KQ4; kq++) {
        uvec2 u = wp[(long)kq * 2048];
        float w0 = bf2f(u.x & 0xffffu), w1 = bf2f(u.x >> 16);
        float w2 = bf2f(u.y & 0xffffu), w3 = bf2f(u.y >> 16);
        float4 x0 = xp[4 * kq], x1 = xp[4 * kq + 1];
        float4 x2 = xp[4 * kq + 2], x3 = xp[4 * kq + 3];
        a0 = fmaf(w0, x0.x, a0); a1 = fmaf(w0, x0.y, a1);
        a2 = fmaf(w0, x0.z, a2); a3 = fmaf(w0, x0.w, a3);
        a0 = fmaf(w1, x1.x, a0); a1 = fmaf(w1, x1.y, a1);
        a2 = fmaf(w1, x1.z, a2); a3 = fmaf(w1, x1.w, a3);
        a0 = fmaf(w2, x2.x, a0); a1 = fmaf(w2, x2.y, a1);
        a2 = fmaf(w2, x2.z, a2); a3 = fmaf(w2, x2.w, a3);
        a0 = fmaf(w3, x3.x, a0); a1 = fmaf(w3, x3.y, a1);
        a2 = fmaf(w3, x3.z, a2); a3 = fmaf(w3, x3.w, a3);
    }
    float4 r4; r4.x = a0; r4.y = a1; r4.z = a2; r4.w = a3;
    ((float4*)sg)[wv * 64 + lane] = r4;
    __syncthreads();
    if (tid < 64) {
        float ga[4];
#pragma unroll
        for (int q = 0; q < 4; q++) {
            int c = q * 16 + gml;
            float sum = 0.f;
#pragma unroll
            for (int w = 0; w < 16; w++) sum += sg[(w * 64 + c) * 4 + gn];
            ga[q] = sum;
        }
        float gi = ga[0] + bi[gm] + bh[gm];
        float gf = ga[1] + bi[512 + gm] + bh[512 + gm];
        float gg = ga[2] + bi[1024 + gm] + bh[1024 + gm];
        float go = ga[3] + bi[1536 + gm] + bh[1536 + gm];
        float si = 1.f / (1.f + expf(-gi));
        float sf = 1.f / (1.f + expf(-gf));
        float so = 1.f / (1.f + expf(-go));
        float c2 = sf * creg + si * tanhf(gg);
        creg = c2;
        float hv = so * tanhf(c2);
        cstore(&hout[(n0 + gn) * 512 + gm], hv);
        if (mlprow) mlprow[(long)(n0 + gn) * 1024 + gm] = hv;
    }
}

// ---------------------------------------------------------------------------
// Persistent decode: 8 groups x 32 blocks x 1024 thr (16 waves, 4/SIMD).
// ---------------------------------------------------------------------------
__global__ __launch_bounds__(1024, 4) void decode_loop(
    const unsigned* __restrict__ Wtb0, const unsigned* __restrict__ Wtb1,
    const unsigned* __restrict__ Wtb2, const float* __restrict__ emb,
    const int* __restrict__ tokens, const float* __restrict__ enc,
    const float* __restrict__ b_ih0, const float* __restrict__ b_hh0,
    const float* __restrict__ b_ih_r, const float* __restrict__ b_hh_r,
    float* __restrict__ hbuf, float* __restrict__ attc,
    float* __restrict__ scor, float* __restrict__ mlpin, int* flags) {
    __shared__ float4 xs4[1536];            // 24KB x-stage / scratch
    __shared__ float sg[4096];              // 16KB partials
    __shared__ unsigned short enct[32768];  // 64KB swizzled enc tile
    float* xsf = (float*)xs4;

    int tid = threadIdx.x, b = blockIdx.x;
    int g = b >> 5, s = b & 31;
    int epoch = 0;
    int n0 = g * 4;
    int lane = tid & 63;
    int gn = tid >> 4, gml = tid & 15;
    int gm = s * 16 + gml;
    int na = n0 + (s >> 3), tiq = s & 7;
    float c0r = 0.f, c1r = 0.f, c2r = 0.f;

    {   // one-time enc tile -> LDS (bf16, swizzled)
        int tl = tid >> 4;
        int gb = (tid & 15) * 4;
        const float* ebase = enc + ((long)na * TI + tiq * 64 + tl) * HH;
#pragma unroll
        for (int q = 0; q < 4; q++) {
            int gg = gb + q;
            const float* ep = ebase + gg * 8;
            float4 lo = *(const float4*)ep;
            float4 hi = *(const float4*)(ep + 4);
            uvec4 pk;
            pk.x = f2bf(lo.x) | (f2bf(lo.y) << 16);
            pk.y = f2bf(lo.z) | (f2bf(lo.w) << 16);
            pk.z = f2bf(hi.x) | (f2bf(hi.y) << 16);
            pk.w = f2bf(hi.z) | (f2bf(hi.w) << 16);
            *(uvec4*)(enct + tl * 512 + (gg ^ (tl & 7)) * 8) = pk;
        }
    }
    __syncthreads();

    for (int t = 0; t < TT; t++) {
        int rp = t & 1;
        float* hOld = hbuf + rp * 3 * NB * HH;
        float* hNew = hbuf + (rp ^ 1) * 3 * NB * HH;
        float* h0r = hOld;
        float* h1r = hOld + NB * HH;
        float* h2r = hOld + 2 * NB * HH;
        float* h0w = hNew;
        float* h1w = hNew + NB * HH;
        float* h2w = hNew + 2 * NB * HH;

        // ===== P1: L0 LSTM, x=[emb|attc|h0r], K=1536 =====
        if (tid < 768) {
            int r0 = (t == 0) ? SOS_ID : tokens[(n0 + 0) * TO + t - 1];
            int r1 = (t == 0) ? SOS_ID : tokens[(n0 + 1) * TO + t - 1];
            int r2 = (t == 0) ? SOS_ID : tokens[(n0 + 2) * TO + t - 1];
            int r3 = (t == 0) ? SOS_ID : tokens[(n0 + 3) * TO + t - 1];
            int k = tid * 2;
            float2 va, vb, vc, vd;
            if (k < 512) {
                va = *(const float2*)(emb + (long)r0 * 512 + k);
                vb = *(const float2*)(emb + (long)r1 * 512 + k);
                vc = *(const float2*)(emb + (long)r2 * 512 + k);
                vd = *(const float2*)(emb + (long)r3 * 512 + k);
            } else if (k < 1024) {
                int kk = k - 512;
                va = cload2(attc + (n0 + 0) * 512 + kk);
                vb = cload2(attc + (n0 + 1) * 512 + kk);
                vc = cload2(attc + (n0 + 2) * 512 + kk);
                vd = cload2(attc + (n0 + 3) * 512 + kk);
                if (t && ((kk >> 4) == s)) {   // exactly-one-block writer
                    float* mp = mlpin + ((long)(t - 1) * NB + n0) * 1024 + 512 + kk;
                    mp[0] = va.x; mp[1] = va.y;
                    mp[1024] = vb.x; mp[1025] = vb.y;
                    mp[2048] = vc.x; mp[2049] = vc.y;
                    mp[3072] = vd.x; mp[3073] = vd.y;
                }
            } else {
                int kk = k - 1024;
                va = cload2(h0r + (n0 + 0) * 512 + kk);
                vb = cload2(h0r + (n0 + 1) * 512 + kk);
                vc = cload2(h0r + (n0 + 2) * 512 + kk);
                vd = cload2(h0r + (n0 + 3) * 512 + kk);
            }
            float4 x0, x1;
            x0.x = va.x; x0.y = vb.x; x0.z = vc.x; x0.w = vd.x;
            x1.x = va.y; x1.y = vb.y; x1.z = vc.y; x1.w = vd.y;
            xs4[k] = x0; xs4[k + 1] = x1;
        }
        __syncthreads();
        lstm_phase<24>(Wtb0, b_ih0, b_hh0, h0w, c0r, nullptr,
                       xs4, sg, s, n0, gn, gml, gm);
        gbar(flags, g, s, epoch);

        // ===== P2: L1 LSTM, x=[h0w|h1r]; zero attc =====
        if (tid < 64) cstore(&attc[n0 * 512 + s * 64 + tid], 0.f);
        if (tid < 512) {
            int k = tid * 2;
            const float* base = (k < 512) ? h0w : (h1r - 512);
            float2 va = cload2(base + (n0 + 0) * 512 + k);
            float2 vb = cload2(base + (n0 + 1) * 512 + k);
            float2 vc = cload2(base + (n0 + 2) * 512 + k);
            float2 vd = cload2(base + (n0 + 3) * 512 + k);
            float4 x0, x1;
            x0.x = va.x; x0.y = vb.x; x0.z = vc.x; x0.w = vd.x;
            x1.x = va.y; x1.y = vb.y; x1.z = vc.y; x1.w = vd.y;
            xs4[k] = x0; xs4[k + 1] = x1;
        }
        __syncthreads();
        lstm_phase<16>(Wtb1, b_ih_r, b_hh_r, h1w, c1r, nullptr,
                       xs4, sg, s, n0, gn, gml, gm);
        gbar(flags, g, s, epoch);

        // ===== P3: L2 LSTM, x=[h1w|h2r] =====
        if (tid < 512) {
            int k = tid * 2;
            const float* base = (k < 512) ? h1w : (h2r - 512);
            float2 va = cload2(base + (n0 + 0) * 512 + k);
            float2 vb = cload2(base + (n0 + 1) * 512 + k);
            float2 vc = cload2(base + (n0 + 2) * 512 + k);
            float2 vd = cload2(base + (n0 + 3) * 512 + k);
            float4 x0, x1;
            x0.x = va.x; x0.y = vb.x; x0.z = vc.x; x0.w = vd.x;
            x1.x = va.y; x1.y = vb.y; x1.z = vc.y; x1.w = vd.y;
            xs4[k] = x0; xs4[k + 1] = x1;
        }
        __syncthreads();
        lstm_phase<16>(Wtb2, b_ih_r + G4, b_hh_r + G4, h2w, c2r,
                       mlpin + (long)t * NB * 1024,
                       xs4, sg, s, n0, gn, gml, gm);
        gbar(flags, g, s, epoch);

        // ===== P4: scores (1024 thr: 64 tl x 16 kh, 4 gg each) =====
        if (tid < 512) xsf[tid] = cload1(h2w + na * 512 + tid);
        __syncthreads();
        {
            int tl = tid & 63, kh = tid >> 6;
            float acc = 0.f;
#pragma unroll
            for (int q = 0; q < 4; q++) {
                int gg = kh * 4 + q;
                uvec4 e = *(const uvec4*)(enct + tl * 512 + ((gg ^ (tl & 7)) * 8));
                const float* hp = xsf + gg * 8;
                acc += bf2f(e.x & 0xffffu) * hp[0] + bf2f(e.x >> 16) * hp[1]
                     + bf2f(e.y & 0xffffu) * hp[2] + bf2f(e.y >> 16) * hp[3]
                     + bf2f(e.z & 0xffffu) * hp[4] + bf2f(e.z >> 16) * hp[5]
                     + bf2f(e.w & 0xffffu) * hp[6] + bf2f(e.w >> 16) * hp[7];
            }
            sg[tid] = acc;
            __syncthreads();
            if (tid < 64) {
                float sv = 0.f;
#pragma unroll
                for (int w = 0; w < 16; w++) sv += sg[tid + 64 * w];
                cstore(&scor[na * 512 + tiq * 64 + tid], sv);
            }
        }
        gbar(flags, g, s, epoch);

        // ===== P5: softmax + apply (atomicAdd into attc) =====
        {
            float sv = (tid < 512) ? cload1(scor + na * 512 + tid) : -1e30f;
            int wv = tid >> 6;
            float m = sv;
#pragma unroll
            for (int o = 32; o > 0; o >>= 1) m = fmaxf(m, __shfl_xor(m, o));
            if (lane == 0) sg[wv] = m;
            __syncthreads();
            m = sg[0];
#pragma unroll
            for (int w = 1; w < 16; w++) m = fmaxf(m, sg[w]);
            float e = expf(sv - m);
            float ss = e;
#pragma unroll
            for (int o = 32; o > 0; o >>= 1) ss += __shfl_xor(ss, o);
            if (lane == 0) sg[32 + wv] = ss;
            __syncthreads();
            float tot = 0.f;
#pragma unroll
            for (int w = 0; w < 16; w++) tot += sg[32 + w];
            float inv = 1.f / tot;
            __syncthreads();
            if (tid < 512) xsf[tid] = e * inv;
            __syncthreads();

            int hp = (tid & 255) * 2, tis = (tid >> 8) * 16;  // 4 quarter-ti
            int gb2 = hp >> 3, wrd = hp & 7;
            const float* wrow = xsf + tiq * 64;
            float a0 = 0.f, a1 = 0.f;
#pragma unroll 8
            for (int q = 0; q < 16; q++) {
                int tl = tis + q;
                unsigned u = *(const unsigned*)(enct + tl * 512 +
                                                ((gb2 ^ (tl & 7)) * 8) + wrd);
                float w = wrow[tl];
                a0 = fmaf(w, bf2f(u & 0xffffu), a0);
                a1 = fmaf(w, bf2f(u >> 16), a1);
            }
            float* prt = xsf + 1024;
            prt[(tid >> 8) * 512 + hp] = a0;
            prt[(tid >> 8) * 512 + hp + 1] = a1;
            __syncthreads();
            if (tid < 512) {
                int h = tid;
                float v = prt[h] + prt[512 + h] + prt[1024 + h] + prt[1536 + h];
                atomicAdd(&attc[na * 512 + h], v);
            }
        }
        gbar(flags, g, s, epoch);
    }

    if (tid < 64) {
        int h = tiq * 64 + tid;
        mlpin[((long)(TT - 1) * NB + na) * 1024 + 512 + h] =
            cload1(attc + na * 512 + h);
    }
}

// ---------------------------------------------------------------------------
// LSTM weight transpose -> bf16 quad-packed, slice-permuted columns.
// ---------------------------------------------------------------------------
__global__ void transpose_lstm_q(const float* __restrict__ Wih, int KA,
                                 const float* __restrict__ Whh,
                                 unsigned* __restrict__ Wtb) {
    int K = KA + 512;
    long total = (long)(K / 4) * 4096;
    for (long idx = (long)blockIdx.x * 256 + threadIdx.x; idx < total;
         idx += (long)gridDim.x * 256) {
        int c2 = (int)(idx % 4096);
        int kq = (int)(idx / 4096);
        int c = c2 >> 1, half = c2 & 1;
        int sI = c >> 6, r = c & 63, gg = r >> 4, ml = r & 15;
        int j = gg * 512 + sI * 16 + ml;
        int k0 = kq * 4 + half * 2, k1 = k0 + 1;
        float w0 = (k0 < KA) ? Wih[(long)j * KA + k0] : Whh[(long)j * 512 + (k0 - KA)];
        float w1 = (k1 < KA) ? Wih[(long)j * KA + k1] : Whh[(long)j * 512 + (k1 - KA)];
        Wtb[idx] = f2bf(w0) | (f2bf(w1) << 16);
    }
}

// W2 -> f16 k-pair packed: Wh[kk][j] = half2(W2[j][2kk], W2[j][2kk+1]), j<10240
__global__ void transpose_w2_h2(const float* __restrict__ W2,
                                unsigned* __restrict__ Wh) {
    long total = (long)256 * 10240;
    for (long idx = (long)blockIdx.x * 256 + threadIdx.x; idx < total;
         idx += (long)gridDim.x * 256) {
        int j = (int)(idx % 10240);
        int kk = (int)(idx / 10240);
        float lo = 0.f, hi = 0.f;
        if (j < VV) {
            lo = W2[(long)j * 512 + 2 * kk];
            hi = W2[(long)j * 512 + 2 * kk + 1];
        }
        Wh[idx] = packh2(lo, hi);
    }
}

// fp32 transpose (MLP1): Wt[k][j] = A[j][k]
__global__ void transpose_cat(const float* __restrict__ A, int KA,
                              int J, int Jp, float* __restrict__ Wt) {
    long total = (long)KA * Jp;
    for (long idx = (long)blockIdx.x * 256 + threadIdx.x; idx < total;
         idx += (long)gridDim.x * 256) {
        int j = (int)(idx % Jp);
        int k = (int)(idx / Jp);
        Wt[idx] = (j < J) ? A[(long)j * KA + k] : 0.f;
    }
}

// ---------------------------------------------------------------------------
// MLP1: 8 rows/block, thread owns adjacent cols (2jp, 2jp+1); f16-pair output.
// grid = 260 blocks x 256 thr.
// ---------------------------------------------------------------------------
__global__ void gemm_mlp1(const float* __restrict__ Wt,
                          const float* __restrict__ X,
                          const float* __restrict__ bias,
                          unsigned* __restrict__ outh) {
    __shared__ float xs[64 * 12];
    int m0 = blockIdx.x * 8;
    int lane = threadIdx.x & 63;
    int wv = threadIdx.x >> 6;
    int jp = wv * 64 + lane;            // 0..255
    float acc0[8], acc1[8];
#pragma unroll
    for (int q = 0; q < 8; q++) { acc0[q] = 0.f; acc1[q] = 0.f; }
    for (int kc = 0; kc < 1024; kc += 64) {
        __syncthreads();
        for (int idx = threadIdx.x; idx < 512; idx += 256) {   // FIXED: full chunk
            int k = idx >> 3, n = idx & 7;
            xs[k * 12 + n] = X[(long)(m0 + n) * 1024 + kc + k];
        }
        __syncthreads();
        const float2* wpp = (const float2*)(Wt + (long)kc * 512) + jp;
#pragma unroll 4
        for (int k = 0; k < 64; k++) {
            float2 w = wpp[(long)k * 256];
            const float4* xv = (const float4*)(xs + k * 12);
            float4 x0 = xv[0], x1 = xv[1];
            acc0[0] += w.x * x0.x; acc0[1] += w.x * x0.y;
            acc0[2] += w.x * x0.z; acc0[3] += w.x * x0.w;
            acc0[4] += w.x * x1.x; acc0[5] += w.x * x1.y;
            acc0[6] += w.x * x1.z; acc0[7] += w.x * x1.w;
            acc1[0] += w.y * x0.x; acc1[1] += w.y * x0.y;
            acc1[2] += w.y * x0.z; acc1[3] += w.y * x0.w;
            acc1[4] += w.y * x1.x; acc1[5] += w.y * x1.y;
            acc1[6] += w.y * x1.z; acc1[7] += w.y * x1.w;
        }
    }
    float b0 = bias[2 * jp], b1 = bias[2 * jp + 1];
#pragma unroll
    for (int n = 0; n < 8; n++) {
        float v0 = tanhf(acc0[n] + b0);
        float v1 = tanhf(acc1[n] + b1);
        outh[(long)(m0 + n) * 256 + jp] = packh2(v0, v1);
    }
}

// ---------------------------------------------------------------------------
// MLP2: f16 dot2 GEMM. Thread owns cols (j0, j0+5120). grid (20, 65) x 256.
// out[(nn*TT+t)*VV + j].
// ---------------------------------------------------------------------------
__global__ void gemm_mlp2(const unsigned* __restrict__ Wh,
                          const unsigned* __restrict__ Xh,
                          const float* __restrict__ bias,
                          float* __restrict__ out) {
    __shared__ unsigned xs[256 * 36];
    int t = blockIdx.y;
    int m0 = t * 32;
    int lane = threadIdx.x & 63;
    int wv = threadIdx.x >> 6;
    int j0 = blockIdx.x * 256 + wv * 64 + lane;   // 0..5119
    float acc0[32], acc1[32];
#pragma unroll
    for (int q = 0; q < 32; q++) { acc0[q] = 0.f; acc1[q] = 0.f; }
    for (int idx = threadIdx.x; idx < 8192; idx += 256) {
        int kk = idx & 255, n = idx >> 8;
        xs[kk * 36 + n] = Xh[(long)(m0 + n) * 256 + kk];
    }
    __syncthreads();
    const unsigned* wpp = Wh + j0;
#pragma unroll 2
    for (int kk = 0; kk < 256; kk++) {
        unsigned u0 = wpp[(long)kk * 10240];
        unsigned u1 = wpp[(long)kk * 10240 + 5120];
        h2v w0 = uash2(u0), w1 = uash2(u1);
        const uvec4* xv = (const uvec4*)(xs + kk * 36);
#pragma unroll
        for (int q = 0; q < 8; q++) {
            uvec4 x4 = xv[q];
            acc0[4 * q + 0] = __builtin_amdgcn_fdot2(uash2(x4.x), w0, acc0[4 * q + 0], false);
            acc0[4 * q + 1] = __builtin_amdgcn_fdot2(uash2(x4.y), w0, acc0[4 * q + 1], false);
            acc0[4 * q + 2] = __builtin_amdgcn_fdot2(uash2(x4.z), w0, acc0[4 * q + 2], false);
            acc0[4 * q + 3] = __builtin_amdgcn_fdot2(uash2(x4.w), w0, acc0[4 * q + 3], false);
            acc1[4 * q + 0] = __builtin_amdgcn_fdot2(uash2(x4.x), w1, acc1[4 * q + 0], false);
            acc1[4 * q + 1] = __builtin_amdgcn_fdot2(uash2(x4.y), w1, acc1[4 * q + 1], false);
            acc1[4 * q + 2] = __builtin_amdgcn_fdot2(uash2(x4.z), w1, acc1[4 * q + 2], false);
            acc1[4 * q + 3] = __builtin_amdgcn_fdot2(uash2(x4.w), w1, acc1[4 * q + 3], false);
        }
    }
#pragma unroll
    for (int nn = 0; nn < 32; nn++) {
        long row = (long)nn * TT + t;
        float* po = out + row * VV;
        int ja = j0, jb = j0 + 5120;
        po[ja] = acc0[nn] + bias[ja];
        if (jb < VV) po[jb] = acc1[nn] + bias[jb];
    }
}

__global__ void loss_rows(const float* __restrict__ out, const int* __restrict__ tokens,
                          float* __restrict__ nll) {
    __shared__ float red[256];
    int row = blockIdx.x;
    int n = row / TT, t = row % TT;
    const float* y = out + (long)row * VV;
    int tid = threadIdx.x;
    float m = -1e30f;
    for (int v = tid; v < VV; v += 256) m = fmaxf(m, y[v]);
    red[tid] = m;
    __syncthreads();
    for (int s = 128; s > 0; s >>= 1) {
        if (tid < s) red[tid] = fmaxf(red[tid], red[tid + s]);
        __syncthreads();
    }
    m = red[0];
    __syncthreads();
    float sum = 0.f;
    for (int v = tid; v < VV; v += 256) sum += expf(y[v] - m);
    red[tid] = sum;
    __syncthreads();
    for (int s = 128; s > 0; s >>= 1) {
        if (tid < s) red[tid] += red[tid + s];
        __syncthreads();
    }
    if (tid == 0) {
        int target = (t < TO) ? tokens[n * TO + t] : EOS_ID;
        nll[row] = m + logf(red[0]) - y[target];
    }
}

__global__ void loss_final(const float* __restrict__ nll, float* __restrict__ out_loss) {
    __shared__ float red[256];
    int tid = threadIdx.x;
    float s = 0.f;
    for (int i = tid; i < NB * TT; i += 256) s += nll[i];
    red[tid] = s;
    __syncthreads();
    for (int k = 128; k > 0; k >>= 1) {
        if (tid < k) red[tid] += red[tid + k];
        __syncthreads();
    }
    if (tid == 0) *out_loss = red[0] / (float)(NB * TT);
}

extern "C" void kernel_launch(void* const* d_in, const int* in_sizes, int n_in,
                              void* d_out, int out_size, void* d_ws, size_t ws_size,
                              hipStream_t stream) {
    const int* padded   = (const int*)d_in[0];
    const float* enc    = (const float*)d_in[1];
    const float* emb    = (const float*)d_in[2];
    const float* W_ih0  = (const float*)d_in[3];
    const float* W_hh0  = (const float*)d_in[4];
    const float* b_ih0  = (const float*)d_in[5];
    const float* b_hh0  = (const float*)d_in[6];
    const float* W_ih_r = (const float*)d_in[7];
    const float* W_hh_r = (const float*)d_in[8];
    const float* b_ih_r = (const float*)d_in[9];
    const float* b_hh_r = (const float*)d_in[10];
    const float* W1     = (const float*)d_in[11];
    const float* b1     = (const float*)d_in[12];
    const float* W2     = (const float*)d_in[13];
    const float* b2     = (const float*)d_in[14];
    float* out = (float*)d_out;
    float* ws  = (float*)d_ws;

    // workspace (dwords)
    unsigned* Wtb0 = (unsigned*)ws;              // [384][4096]
    unsigned* Wtb1 = Wtb0 + 384 * 4096;          // [256][4096]
    unsigned* Wtb2 = Wtb1 + 256 * 4096;          // [256][4096]
    unsigned* Wh   = Wtb2 + 256 * 4096;          // [256][10240]
    float* Wm1  = (float*)(Wh + 256 * 10240);    // [1024][512]
    float* hbuf = Wm1 + 1024 * 512;              // [2][3][32][512]
    float* attc = hbuf + 2 * 3 * NB * HH;        // [32][512]
    float* scor = attc + NB * HH;                // [32][512]
    float* mlpin= scor + NB * TI;                // [65][32][1024]
    unsigned* y1h = (unsigned*)(mlpin + (long)TT * NB * 1024);  // [2080][256]
    float* nll  = (float*)(y1h + (long)TT * NB * 256);          // [2080]
    int*   flags= (int*)(nll + 2080);            // [8][32][16]

    hipMemsetAsync(hbuf, 0, (size_t)(2 * 3 * NB * HH + 2 * NB * HH) * sizeof(float), stream);
    hipMemsetAsync(flags, 0, 8 * 32 * 16 * sizeof(int), stream);

    transpose_cat<<<1024, 256, 0, stream>>>(W1, 1024, 512, 512, Wm1);
    transpose_lstm_q<<<2048, 256, 0, stream>>>(W_ih0, 1024, W_hh0, Wtb0);
    transpose_lstm_q<<<2048, 256, 0, stream>>>(W_ih_r, 512, W_hh_r, Wtb1);
    transpose_lstm_q<<<2048, 256, 0, stream>>>(W_ih_r + 2048 * 512, 512,
                                               W_hh_r + 2048 * 512, Wtb2);
    transpose_w2_h2<<<2048, 256, 0, stream>>>(W2, Wh);

    decode_loop<<<NBLK, 1024, 0, stream>>>(Wtb0, Wtb1, Wtb2, emb, padded, enc,
                                           b_ih0, b_hh0, b_ih_r, b_hh_r,
                                           hbuf, attc, scor, mlpin, flags);

    gemm_mlp1<<<260, 256, 0, stream>>>(Wm1, mlpin, b1, y1h);
    gemm_mlp2<<<dim3(20, TT), 256, 0, stream>>>(Wh, y1h, b2, out);
    loss_rows<<<NB * TT, 256, 0, stream>>>(out, padded, nll);
    loss_final<<<1, 256, 0, stream>>>(nll, out + (long)NB * TT * VV);
}